// Round 1
// baseline (1143.879 us; speedup 1.0000x reference)
//
#include <hip/hip_runtime.h>
#include <math.h>

#define DI __device__ __forceinline__

constexpr int Hh   = 128;
constexpr int Ww   = 128;
constexpr int WF   = 65;            // W/2+1
constexpr int NBIN = Hh * WF;       // 8320
constexpr int NB   = 32;            // batch
constexpr int CIN  = 64;
constexpr int COUT = 128;
constexpr int HO   = 120;
constexpr int WO   = 120;

// ---------------------------------------------------------------------------
// 128-point radix-2 Stockham FFT in LDS. 64 lanes (one wave) per sequence,
// but __syncthreads() between stages keeps all 4 groups of a 256-thread block
// in lockstep (correctness-first; wave-local sync is a later optimization).
// Input in s[0..127]; returns pointer to result buffer (ends in d after 7
// stages -> returned pointer). inv!=0 => conjugate twiddles (NO 1/N scale).
// ---------------------------------------------------------------------------
DI float2* fft128(float2* s, float2* d, const float2* tw, int lane, int inv) {
#pragma unroll
  for (int st = 0; st < 7; ++st) {
    const int m  = 1 << st;
    const int tj = lane & ~(m - 1);        // j*m
    float2 c0 = s[lane];
    float2 c1 = s[lane + 64];
    float2 w  = tw[tj];                    // exp(-i*pi*(j*m)/64)
    float  wy = inv ? -w.y : w.y;
    float  sx = c0.x + c1.x, sy = c0.y + c1.y;
    float  dx = c0.x - c1.x, dy = c0.y - c1.y;
    float2 wd = make_float2(w.x * dx - wy * dy, w.x * dy + wy * dx);
    const int di = lane + tj;
    d[di]     = make_float2(sx, sy);
    d[di + m] = wd;
    __syncthreads();
    float2* t_ = s; s = d; d = t_;
  }
  return s;   // after 7 swaps this points at the last-written buffer
}

// ---------------------------------------------------------------------------
// Forward: one block per (b, i) image. real 128x128 -> complex 128x65.
// ---------------------------------------------------------------------------
__global__ __launch_bounds__(256) void fwd_fft(const float* __restrict__ sig,
                                               float2* __restrict__ sf) {
  __shared__ __align__(16) float2 sImg[Hh * WF];   // 66560 B
  __shared__ float2 bufA[4][128];
  __shared__ float2 bufB[4][128];
  __shared__ float2 tw[64];

  const int t = threadIdx.x, grp = t >> 6, lane = t & 63;
  const size_t img = blockIdx.x;
  const float* src = sig + img * (size_t)(Hh * Ww);
  float2* dst = sf + img * (size_t)NBIN;

  if (t < 64) {
    float s_, c_;
    sincosf(-(float)M_PI * (float)t / 64.f, &s_, &c_);
    tw[t] = make_float2(c_, s_);
  }
  __syncthreads();

  // ---- phase 1: row rfft via two-real-rows-in-one-complex-FFT trick ----
  for (int batch = 0; batch < 16; ++batch) {
    const int j = batch * 4 + grp;               // row pair 0..63
    const float* r0 = src + (size_t)(2 * j) * Ww;
    bufA[grp][lane]      = make_float2(r0[lane],      r0[Ww + lane]);
    bufA[grp][lane + 64] = make_float2(r0[lane + 64], r0[Ww + lane + 64]);
    __syncthreads();
    float2* Z = fft128(bufA[grp], bufB[grp], tw, lane, 0);
    // unpack: X0[k] = (Z[k]+conj(Z[-k]))/2 ; X1[k] = -i(Z[k]-conj(Z[-k]))/2
    float2 Zk = Z[lane];
    float2 Zm = Z[(128 - lane) & 127];
    float2 X0 = make_float2(0.5f * (Zk.x + Zm.x), 0.5f * (Zk.y - Zm.y));
    float2 X1 = make_float2(0.5f * (Zk.y + Zm.y), 0.5f * (Zm.x - Zk.x));
    sImg[(2 * j) * WF + lane]     = X0;
    sImg[(2 * j + 1) * WF + lane] = X1;
    if (lane == 0) {
      float2 Z64 = Z[64];
      sImg[(2 * j) * WF + 64]     = make_float2(Z64.x, 0.f);
      sImg[(2 * j + 1) * WF + 64] = make_float2(Z64.y, 0.f);
    }
    __syncthreads();
  }

  // ---- phase 2: complex FFT along H for each of the 65 columns ----
  for (int batch = 0; batch < 17; ++batch) {
    const int w  = batch * 4 + grp;
    const int wc = (w < WF) ? w : (WF - 1);      // idle groups clamp (uniform barriers)
    bufA[grp][lane]      = sImg[lane * WF + wc];
    bufA[grp][lane + 64] = sImg[(lane + 64) * WF + wc];
    __syncthreads();
    float2* R = fft128(bufA[grp], bufB[grp], tw, lane, 0);
    if (w < WF) {
      sImg[lane * WF + w]        = R[lane];
      sImg[(lane + 64) * WF + w] = R[lane + 64];
    }
    __syncthreads();
  }

  // ---- coalesced copy-out ----
  const float4* s4 = (const float4*)sImg;
  float4* d4 = (float4*)dst;
  for (int idx = t; idx < (NBIN * 2) / 4; idx += 256) d4[idx] = s4[idx];
}

// ---------------------------------------------------------------------------
// Spectral contraction: out_fr[b,o,p] = sum_i sig_fr[b,i,p] * ker[o,i,p]
// Block: 8 consecutive bins x all 32 b x 32-wide o tile. 256 threads.
// Thread: bin = t&7, group g=t>>3 -> (bq=g>>2, oq=g&3) owns 4 b x 8 o accs.
// ---------------------------------------------------------------------------
__global__ __launch_bounds__(256) void spec_mm(const float2* __restrict__ sf,
                                               const float*  __restrict__ wr,
                                               const float*  __restrict__ wi,
                                               float2* __restrict__ of) {
  __shared__ float2 ssig[32][8];
  __shared__ float  skr[32][8];
  __shared__ float  ski[32][8];

  const int p0 = blockIdx.x * 8;
  const int o0 = blockIdx.y * 32;
  const int t = threadIdx.x;
  const int binl = t & 7, g = t >> 3;          // g: 0..31
  const int bq = g >> 2, oq = g & 3;

  float2 acc[4][8];
#pragma unroll
  for (int x = 0; x < 4; ++x)
#pragma unroll
    for (int y = 0; y < 8; ++y) acc[x][y] = make_float2(0.f, 0.f);

  for (int i = 0; i < CIN; ++i) {
    ssig[g][binl] = sf[((size_t)g * CIN + i) * NBIN + p0 + binl];        // g == b
    const size_t wo = ((size_t)(o0 + g) * CIN + i) * NBIN + p0 + binl;   // g == o-local
    skr[g][binl] = wr[wo];
    ski[g][binl] = wi[wo];
    __syncthreads();

    float2 s0[4];
    float  kr[8], ki[8];
#pragma unroll
    for (int x = 0; x < 4; ++x) s0[x] = ssig[bq * 4 + x][binl];
#pragma unroll
    for (int y = 0; y < 8; ++y) { kr[y] = skr[oq * 8 + y][binl]; ki[y] = ski[oq * 8 + y][binl]; }
#pragma unroll
    for (int x = 0; x < 4; ++x)
#pragma unroll
      for (int y = 0; y < 8; ++y) {
        acc[x][y].x = fmaf(s0[x].x, kr[y], fmaf(-s0[x].y, ki[y], acc[x][y].x));
        acc[x][y].y = fmaf(s0[x].x, ki[y], fmaf( s0[x].y, kr[y], acc[x][y].y));
      }
    __syncthreads();
  }

  const int p = p0 + binl;
#pragma unroll
  for (int x = 0; x < 4; ++x)
#pragma unroll
    for (int y = 0; y < 8; ++y) {
      const size_t b = (size_t)(bq * 4 + x);
      const size_t o = (size_t)(o0 + oq * 8 + y);
      of[(b * COUT + o) * NBIN + p] = acc[x][y];
    }
}

// ---------------------------------------------------------------------------
// Inverse: one block per (b, o) image. complex 128x65 -> real 120x120 (+bias).
// ifft along H (65 cols), then irfft along W via pair trick (pocketfft C2R
// semantics: imag parts of DC & Nyquist bins are ignored -> zero them).
// ---------------------------------------------------------------------------
__global__ __launch_bounds__(256) void inv_fft(const float2* __restrict__ of,
                                               const float*  __restrict__ bias,
                                               float* __restrict__ out) {
  __shared__ __align__(16) float2 sImg[Hh * WF];
  __shared__ float2 bufA[4][128];
  __shared__ float2 bufB[4][128];
  __shared__ float2 tw[64];

  const int t = threadIdx.x, grp = t >> 6, lane = t & 63;
  const size_t img = blockIdx.x;                 // b*COUT + o
  const float2* src = of + img * (size_t)NBIN;
  float* dst = out + img * (size_t)(HO * WO);
  const float bo = bias[img & (COUT - 1)];

  if (t < 64) {
    float s_, c_;
    sincosf(-(float)M_PI * (float)t / 64.f, &s_, &c_);
    tw[t] = make_float2(c_, s_);
  }
  __syncthreads();

  // ---- load spectrum ----
  const float4* s4 = (const float4*)src;
  float4* d4 = (float4*)sImg;
  for (int idx = t; idx < (NBIN * 2) / 4; idx += 256) d4[idx] = s4[idx];
  __syncthreads();

  // ---- inverse complex FFT along H on 65 columns ----
  for (int batch = 0; batch < 17; ++batch) {
    const int w  = batch * 4 + grp;
    const int wc = (w < WF) ? w : (WF - 1);
    bufA[grp][lane]      = sImg[lane * WF + wc];
    bufA[grp][lane + 64] = sImg[(lane + 64) * WF + wc];
    __syncthreads();
    float2* R = fft128(bufA[grp], bufB[grp], tw, lane, 1);
    if (w < WF) {
      sImg[lane * WF + w]        = R[lane];
      sImg[(lane + 64) * WF + w] = R[lane + 64];
    }
    __syncthreads();
  }

  // ---- irfft along W, two rows per complex iFFT; crop to 120x120 ----
  const float scale = 1.f / 16384.f;
  for (int batch = 0; batch < 15; ++batch) {       // row pairs 0..59 (rows 0..119)
    const int j = batch * 4 + grp;
    const float2* X0p = &sImg[(size_t)(2 * j) * WF];
    const float2* X1p = &sImg[(size_t)(2 * j + 1) * WF];
    float2 za, zb;
    if (lane == 0) {
      za = make_float2(X0p[0].x,  X1p[0].x);       // DC: drop imag (C2R semantics)
      zb = make_float2(X0p[64].x, X1p[64].x);      // Nyquist: drop imag
    } else {
      float2 x0 = X0p[lane], x1 = X1p[lane];
      za = make_float2(x0.x - x1.y, x0.y + x1.x);  // Z[k] = X0[k] + i X1[k]
      const int mI = 64 - lane;                    // 1..63
      float2 y0 = X0p[mI], y1 = X1p[mI];
      zb = make_float2(y0.x + y1.y, y1.x - y0.y);  // Z[128-m] = conj(X0)+i conj(X1)
    }
    bufA[grp][lane]      = za;
    bufA[grp][lane + 64] = zb;
    __syncthreads();
    float2* R = fft128(bufA[grp], bufB[grp], tw, lane, 1);
    float2 v0 = R[lane];
    dst[(size_t)(2 * j) * WO + lane]     = v0.x * scale + bo;
    dst[(size_t)(2 * j + 1) * WO + lane] = v0.y * scale + bo;
    if (lane < WO - 64) {                          // lane < 56
      float2 v1 = R[lane + 64];
      dst[(size_t)(2 * j) * WO + lane + 64]     = v1.x * scale + bo;
      dst[(size_t)(2 * j + 1) * WO + lane + 64] = v1.y * scale + bo;
    }
    __syncthreads();
  }
}

// ---------------------------------------------------------------------------
extern "C" void kernel_launch(void* const* d_in, const int* in_sizes, int n_in,
                              void* d_out, int out_size, void* d_ws, size_t ws_size,
                              hipStream_t stream) {
  const float* signal = (const float*)d_in[0];
  const float* wr     = (const float*)d_in[1];
  const float* wi     = (const float*)d_in[2];
  const float* bias   = (const float*)d_in[3];
  float* out = (float*)d_out;

  // sig_fr (B*CIN*NBIN complex = 136.3 MB) lives in d_out (235.9 MB) -- it is
  // fully dead before inv_fft overwrites d_out with the real result.
  // out_fr (B*COUT*NBIN complex = 272.6 MB) lives in d_ws.
  float2* sig_fr = (float2*)d_out;
  float2* out_fr = (float2*)d_ws;
  (void)in_sizes; (void)n_in; (void)out_size; (void)ws_size;

  fwd_fft<<<NB * CIN, 256, 0, stream>>>(signal, sig_fr);
  spec_mm<<<dim3(NBIN / 8, COUT / 32), 256, 0, stream>>>(sig_fr, wr, wi, out_fr);
  inv_fft<<<NB * COUT, 256, 0, stream>>>(out_fr, bias, out);
}

// Round 2
// 967.945 us; speedup vs baseline: 1.1818x; 1.1818x over previous
//
#include <hip/hip_runtime.h>
#include <math.h>

#define DI __device__ __forceinline__

constexpr int Hh   = 128;
constexpr int Ww   = 128;
constexpr int WF   = 65;            // W/2+1
constexpr int NBIN = Hh * WF;       // 8320
constexpr int NB   = 32;            // batch
constexpr int CIN  = 64;
constexpr int COUT = 128;
constexpr int HO   = 120;
constexpr int WO   = 120;

// Wave-local LDS sync: each 64-lane group owns its FFT ping-pong buffers, so
// cross-lane LDS visibility within the wave only needs the LDS queue drained
// (wave is lockstep). sched_barrier keeps the compiler from hoisting
// dependent ops above the wait (guide rule #18).
DI void wsync() {
  asm volatile("s_waitcnt lgkmcnt(0)" ::: "memory");
  __builtin_amdgcn_sched_barrier(0);
}

// ---------------------------------------------------------------------------
// 128-point radix-2 Stockham FFT in LDS, one wave per sequence, wave-local
// sync only. Input in s[0..127]; returns pointer to result buffer.
// inv!=0 => conjugate twiddles (NO 1/N scale).
// ---------------------------------------------------------------------------
DI float2* fft128(float2* s, float2* d, const float2* tw, int lane, int inv) {
  wsync();                               // staging writes -> visible to wave
#pragma unroll
  for (int st = 0; st < 7; ++st) {
    const int m  = 1 << st;
    const int tj = lane & ~(m - 1);      // j*m
    float2 c0 = s[lane];
    float2 c1 = s[lane + 64];
    float2 w  = tw[tj];                  // exp(-i*pi*(j*m)/64)
    float  wy = inv ? -w.y : w.y;
    float  sx = c0.x + c1.x, sy = c0.y + c1.y;
    float  dx = c0.x - c1.x, dy = c0.y - c1.y;
    float2 wd = make_float2(w.x * dx - wy * dy, w.x * dy + wy * dx);
    const int di = lane + tj;
    d[di]     = make_float2(sx, sy);
    d[di + m] = wd;
    wsync();
    float2* t_ = s; s = d; d = t_;
  }
  return s;
}

// ---------------------------------------------------------------------------
// Forward: one block per (b, i) image. real 128x128 -> complex 128x65.
// Block barriers only at phase boundaries (3 total).
// ---------------------------------------------------------------------------
__global__ __launch_bounds__(256) void fwd_fft(const float* __restrict__ sig,
                                               float2* __restrict__ sf) {
  __shared__ __align__(16) float2 sImg[Hh * WF];   // 66560 B
  __shared__ float2 bufA[4][128];
  __shared__ float2 bufB[4][128];
  __shared__ float2 tw[64];

  const int t = threadIdx.x, grp = t >> 6, lane = t & 63;
  const size_t img = blockIdx.x;
  const float* src = sig + img * (size_t)(Hh * Ww);
  float2* dst = sf + img * (size_t)NBIN;

  if (t < 64) {
    float s_, c_;
    sincosf(-(float)M_PI * (float)t / 64.f, &s_, &c_);
    tw[t] = make_float2(c_, s_);
  }
  __syncthreads();

  // ---- phase 1: row rfft via two-real-rows-in-one-complex-FFT trick ----
  for (int batch = 0; batch < 16; ++batch) {
    const int j = batch * 4 + grp;               // row pair 0..63
    const float* r0 = src + (size_t)(2 * j) * Ww;
    bufA[grp][lane]      = make_float2(r0[lane],      r0[Ww + lane]);
    bufA[grp][lane + 64] = make_float2(r0[lane + 64], r0[Ww + lane + 64]);
    float2* Z = fft128(bufA[grp], bufB[grp], tw, lane, 0);
    float2 Zk = Z[lane];
    float2 Zm = Z[(128 - lane) & 127];
    float2 X0 = make_float2(0.5f * (Zk.x + Zm.x), 0.5f * (Zk.y - Zm.y));
    float2 X1 = make_float2(0.5f * (Zk.y + Zm.y), 0.5f * (Zm.x - Zk.x));
    sImg[(2 * j) * WF + lane]     = X0;
    sImg[(2 * j + 1) * WF + lane] = X1;
    if (lane == 0) {
      float2 Z64 = Z[64];
      sImg[(2 * j) * WF + 64]     = make_float2(Z64.x, 0.f);
      sImg[(2 * j + 1) * WF + 64] = make_float2(Z64.y, 0.f);
    }
  }
  __syncthreads();

  // ---- phase 2: complex FFT along H, disjoint columns per group ----
  for (int batch = 0; batch < 17; ++batch) {
    const int w  = batch * 4 + grp;
    const int wc = (w < WF) ? w : (WF - 1);      // idle groups clamp (discarded)
    bufA[grp][lane]      = sImg[lane * WF + wc];
    bufA[grp][lane + 64] = sImg[(lane + 64) * WF + wc];
    float2* R = fft128(bufA[grp], bufB[grp], tw, lane, 0);
    if (w < WF) {
      sImg[lane * WF + w]        = R[lane];
      sImg[(lane + 64) * WF + w] = R[lane + 64];
    }
  }
  __syncthreads();

  // ---- coalesced copy-out ----
  const float4* s4 = (const float4*)sImg;
  float4* d4 = (float4*)dst;
  for (int idx = t; idx < (NBIN * 2) / 4; idx += 256) d4[idx] = s4[idx];
}

// ---------------------------------------------------------------------------
// Spectral contraction: out_fr[b,o,p] = sum_i sig_fr[b,i,p] * ker[o,i,p]
// Block: 8 bins x all 32 b x 64-wide o tile. 256 threads; thread owns an
// 8b x 8o complex register tile for one bin. i staged in chunks of 8.
// ---------------------------------------------------------------------------
__global__ __launch_bounds__(256, 2) void spec_mm(const float2* __restrict__ sf,
                                                  const float*  __restrict__ wr,
                                                  const float*  __restrict__ wi,
                                                  float2* __restrict__ of) {
  __shared__ float2 ssig[8][32][8];     // [ic][b][bin]   16 KB
  __shared__ float  skr[8][64][9];      // [ic][o][bin+pad] 18 KB (stride 9 -> 2-way max)
  __shared__ float  ski[8][64][9];      // 18 KB

  const int p0 = blockIdx.x * 8;
  const int o0 = blockIdx.y * 64;
  const int t = threadIdx.x;
  const int binl = t & 7;
  const int g = t >> 3;                 // 0..31
  const int oq = g & 7;                 // o sub-tile 0..7
  const int bq = g >> 3;                // b sub-tile 0..3

  float2 acc[8][8];
#pragma unroll
  for (int x = 0; x < 8; ++x)
#pragma unroll
    for (int y = 0; y < 8; ++y) acc[x][y] = make_float2(0.f, 0.f);

  for (int i0 = 0; i0 < CIN; i0 += 8) {
    // ---- stage sig: 32b x 8i x 8bins float2 = 1024 float4 ----
#pragma unroll
    for (int r = 0; r < 4; ++r) {
      const int idx = r * 256 + t;
      const int f4 = idx & 3;           // float4 within the 8-float2 bin run
      const int bi = idx >> 2;
      const int b  = bi >> 3, ic = bi & 7;
      const float4 v = *(const float4*)(&sf[((size_t)b * CIN + i0 + ic) * NBIN + p0] ) + f4 == 0
                       ? *((const float4*)(&sf[((size_t)b * CIN + i0 + ic) * NBIN + p0]) + f4)
                       : *((const float4*)(&sf[((size_t)b * CIN + i0 + ic) * NBIN + p0]) + f4);
      ((float4*)&ssig[ic][b][0])[f4] = v;
    }
    // ---- stage weights: 64o x 8i x 8bins floats = 1024 float4 each ----
#pragma unroll
    for (int r = 0; r < 4; ++r) {
      const int idx = r * 256 + t;
      const int f4 = idx & 1;           // which half of the 8-float bin run
      const int oi = idx >> 1;
      const int o  = oi >> 3, ic = oi & 7;
      const size_t gaddr = ((size_t)(o0 + o) * CIN + i0 + ic) * NBIN + p0 + f4 * 4;
      const float4 vr = *(const float4*)(wr + gaddr);
      const float4 vi = *(const float4*)(wi + gaddr);
      float* pr = &skr[ic][o][f4 * 4];
      float* pi = &ski[ic][o][f4 * 4];
      pr[0] = vr.x; pr[1] = vr.y; pr[2] = vr.z; pr[3] = vr.w;
      pi[0] = vi.x; pi[1] = vi.y; pi[2] = vi.z; pi[3] = vi.w;
    }
    __syncthreads();

    for (int ic = 0; ic < 8; ++ic) {
      float2 s0[8];
      float  kr[8], ki[8];
#pragma unroll
      for (int x = 0; x < 8; ++x) s0[x] = ssig[ic][bq * 8 + x][binl];
#pragma unroll
      for (int y = 0; y < 8; ++y) {
        kr[y] = skr[ic][oq * 8 + y][binl];
        ki[y] = ski[ic][oq * 8 + y][binl];
      }
#pragma unroll
      for (int x = 0; x < 8; ++x)
#pragma unroll
        for (int y = 0; y < 8; ++y) {
          acc[x][y].x = fmaf(s0[x].x, kr[y], fmaf(-s0[x].y, ki[y], acc[x][y].x));
          acc[x][y].y = fmaf(s0[x].x, ki[y], fmaf( s0[x].y, kr[y], acc[x][y].y));
        }
    }
    __syncthreads();
  }

  const int p = p0 + binl;
#pragma unroll
  for (int x = 0; x < 8; ++x)
#pragma unroll
    for (int y = 0; y < 8; ++y) {
      const size_t b = (size_t)(bq * 8 + x);
      const size_t o = (size_t)(o0 + oq * 8 + y);
      of[(b * COUT + o) * NBIN + p] = acc[x][y];
    }
}

// ---------------------------------------------------------------------------
// Inverse: one block per (b, o) image. complex 128x65 -> real 120x120 (+bias).
// ---------------------------------------------------------------------------
__global__ __launch_bounds__(256) void inv_fft(const float2* __restrict__ of,
                                               const float*  __restrict__ bias,
                                               float* __restrict__ out) {
  __shared__ __align__(16) float2 sImg[Hh * WF];
  __shared__ float2 bufA[4][128];
  __shared__ float2 bufB[4][128];
  __shared__ float2 tw[64];

  const int t = threadIdx.x, grp = t >> 6, lane = t & 63;
  const size_t img = blockIdx.x;                 // b*COUT + o
  const float2* src = of + img * (size_t)NBIN;
  float* dst = out + img * (size_t)(HO * WO);
  const float bo = bias[img & (COUT - 1)];

  if (t < 64) {
    float s_, c_;
    sincosf(-(float)M_PI * (float)t / 64.f, &s_, &c_);
    tw[t] = make_float2(c_, s_);
  }

  // ---- load spectrum ----
  const float4* s4 = (const float4*)src;
  float4* d4 = (float4*)sImg;
  for (int idx = t; idx < (NBIN * 2) / 4; idx += 256) d4[idx] = s4[idx];
  __syncthreads();

  // ---- inverse complex FFT along H, disjoint columns per group ----
  for (int batch = 0; batch < 17; ++batch) {
    const int w  = batch * 4 + grp;
    const int wc = (w < WF) ? w : (WF - 1);
    bufA[grp][lane]      = sImg[lane * WF + wc];
    bufA[grp][lane + 64] = sImg[(lane + 64) * WF + wc];
    float2* R = fft128(bufA[grp], bufB[grp], tw, lane, 1);
    if (w < WF) {
      sImg[lane * WF + w]        = R[lane];
      sImg[(lane + 64) * WF + w] = R[lane + 64];
    }
  }
  __syncthreads();

  // ---- irfft along W, two rows per complex iFFT; crop to 120x120 ----
  const float scale = 1.f / 16384.f;
  for (int batch = 0; batch < 15; ++batch) {       // row pairs 0..59
    const int j = batch * 4 + grp;
    const float2* X0p = &sImg[(size_t)(2 * j) * WF];
    const float2* X1p = &sImg[(size_t)(2 * j + 1) * WF];
    float2 za, zb;
    if (lane == 0) {
      za = make_float2(X0p[0].x,  X1p[0].x);       // DC: drop imag (C2R)
      zb = make_float2(X0p[64].x, X1p[64].x);      // Nyquist: drop imag
    } else {
      float2 x0 = X0p[lane], x1 = X1p[lane];
      za = make_float2(x0.x - x1.y, x0.y + x1.x);  // Z[k] = X0[k] + i X1[k]
      const int mI = 64 - lane;                    // 1..63
      float2 y0 = X0p[mI], y1 = X1p[mI];
      zb = make_float2(y0.x + y1.y, y1.x - y0.y);  // Z[128-m]
    }
    bufA[grp][lane]      = za;
    bufA[grp][lane + 64] = zb;
    float2* R = fft128(bufA[grp], bufB[grp], tw, lane, 1);
    float2 v0 = R[lane];
    dst[(size_t)(2 * j) * WO + lane]     = v0.x * scale + bo;
    dst[(size_t)(2 * j + 1) * WO + lane] = v0.y * scale + bo;
    if (lane < WO - 64) {                          // lane < 56
      float2 v1 = R[lane + 64];
      dst[(size_t)(2 * j) * WO + lane + 64]     = v1.x * scale + bo;
      dst[(size_t)(2 * j + 1) * WO + lane + 64] = v1.y * scale + bo;
    }
  }
}

// ---------------------------------------------------------------------------
extern "C" void kernel_launch(void* const* d_in, const int* in_sizes, int n_in,
                              void* d_out, int out_size, void* d_ws, size_t ws_size,
                              hipStream_t stream) {
  const float* signal = (const float*)d_in[0];
  const float* wr     = (const float*)d_in[1];
  const float* wi     = (const float*)d_in[2];
  const float* bias   = (const float*)d_in[3];
  float* out = (float*)d_out;

  // sig_fr (136.3 MB) lives in d_out (235.9 MB) -- dead before inv_fft writes.
  // out_fr (272.6 MB) lives in d_ws.
  float2* sig_fr = (float2*)d_out;
  float2* out_fr = (float2*)d_ws;
  (void)in_sizes; (void)n_in; (void)out_size; (void)ws_size;

  fwd_fft<<<NB * CIN, 256, 0, stream>>>(signal, sig_fr);
  spec_mm<<<dim3(NBIN / 8, COUT / 64), 256, 0, stream>>>(sig_fr, wr, wi, out_fr);
  inv_fft<<<NB * COUT, 256, 0, stream>>>(out_fr, bias, out);
}

// Round 3
// 897.694 us; speedup vs baseline: 1.2742x; 1.0783x over previous
//
#include <hip/hip_runtime.h>
#include <math.h>

#define DI __device__ __forceinline__

constexpr int Hh   = 128;
constexpr int Ww   = 128;
constexpr int WF   = 65;            // W/2+1
constexpr int NBIN = Hh * WF;       // 8320
constexpr int NB   = 32;            // batch
constexpr int CIN  = 64;
constexpr int COUT = 128;
constexpr int HO   = 120;
constexpr int WO   = 120;

typedef __bf16 bf16x8 __attribute__((ext_vector_type(8)));
typedef float  f32x4  __attribute__((ext_vector_type(4)));

// ---- bf16 pack/unpack (RNE) ----
DI unsigned int bfbits(float x) {
  unsigned int u = __float_as_uint(x);
  return (u + 0x7FFFu + ((u >> 16) & 1u)) >> 16;
}
DI unsigned int packbf(float re, float im) { return bfbits(re) | (bfbits(im) << 16); }
DI float2 unpackbf(unsigned int v) {
  return make_float2(__uint_as_float(v << 16), __uint_as_float(v & 0xFFFF0000u));
}

DI f32x4 MFMA16(uint4 a, uint4 b, f32x4 c) {
  return __builtin_amdgcn_mfma_f32_16x16x32_bf16(
      __builtin_bit_cast(bf16x8, a), __builtin_bit_cast(bf16x8, b), c, 0, 0, 0);
}
// S=[Sr,Si] per u32 -> S'=[Si,-Sr]
DI unsigned int rotneg(unsigned int x) { return ((x << 16) | (x >> 16)) ^ 0x80000000u; }
DI uint4 derive(uint4 s) {
  uint4 r; r.x = rotneg(s.x); r.y = rotneg(s.y); r.z = rotneg(s.z); r.w = rotneg(s.w);
  return r;
}

// Wave-local LDS sync for the FFT ping-pong (one wave owns its buffers).
DI void wsync() {
  asm volatile("s_waitcnt lgkmcnt(0)" ::: "memory");
  __builtin_amdgcn_sched_barrier(0);
}

// ---------------------------------------------------------------------------
// 128-point radix-2 Stockham FFT in LDS, one wave per sequence.
// ---------------------------------------------------------------------------
DI float2* fft128(float2* s, float2* d, const float2* tw, int lane, int inv) {
  wsync();
#pragma unroll
  for (int st = 0; st < 7; ++st) {
    const int m  = 1 << st;
    const int tj = lane & ~(m - 1);
    float2 c0 = s[lane];
    float2 c1 = s[lane + 64];
    float2 w  = tw[tj];
    float  wy = inv ? -w.y : w.y;
    float  sx = c0.x + c1.x, sy = c0.y + c1.y;
    float  dx = c0.x - c1.x, dy = c0.y - c1.y;
    float2 wd = make_float2(w.x * dx - wy * dy, w.x * dy + wy * dx);
    const int di = lane + tj;
    d[di]     = make_float2(sx, sy);
    d[di + m] = wd;
    wsync();
    float2* t_ = s; s = d; d = t_;
  }
  return s;
}

// ---------------------------------------------------------------------------
// Forward: one block per (b, i). real 128x128 -> packed bf16 complex 128x65.
// ---------------------------------------------------------------------------
__global__ __launch_bounds__(256) void fwd_fft(const float* __restrict__ sig,
                                               unsigned int* __restrict__ sf) {
  __shared__ unsigned int sImg[NBIN];        // 33280 B, packed bf16 pairs
  __shared__ float2 bufA[4][128];
  __shared__ float2 bufB[4][128];
  __shared__ float2 tw[64];

  const int t = threadIdx.x, grp = t >> 6, lane = t & 63;
  const size_t img = blockIdx.x;
  const float* src = sig + img * (size_t)(Hh * Ww);
  unsigned int* dst = sf + img * (size_t)NBIN;

  if (t < 64) {
    float s_, c_;
    sincosf(-(float)M_PI * (float)t / 64.f, &s_, &c_);
    tw[t] = make_float2(c_, s_);
  }
  __syncthreads();

  // phase 1: row rfft (two real rows per complex FFT)
  for (int batch = 0; batch < 16; ++batch) {
    const int j = batch * 4 + grp;
    const float* r0 = src + (size_t)(2 * j) * Ww;
    bufA[grp][lane]      = make_float2(r0[lane],      r0[Ww + lane]);
    bufA[grp][lane + 64] = make_float2(r0[lane + 64], r0[Ww + lane + 64]);
    float2* Z = fft128(bufA[grp], bufB[grp], tw, lane, 0);
    float2 Zk = Z[lane];
    float2 Zm = Z[(128 - lane) & 127];
    sImg[(2 * j) * WF + lane]     = packbf(0.5f * (Zk.x + Zm.x), 0.5f * (Zk.y - Zm.y));
    sImg[(2 * j + 1) * WF + lane] = packbf(0.5f * (Zk.y + Zm.y), 0.5f * (Zm.x - Zk.x));
    if (lane == 0) {
      float2 Z64 = Z[64];
      sImg[(2 * j) * WF + 64]     = packbf(Z64.x, 0.f);
      sImg[(2 * j + 1) * WF + 64] = packbf(Z64.y, 0.f);
    }
  }
  __syncthreads();

  // phase 2: complex FFT along H, disjoint columns per group
  for (int batch = 0; batch < 17; ++batch) {
    const int w  = batch * 4 + grp;
    const int wc = (w < WF) ? w : (WF - 1);
    float2 t0 = unpackbf(sImg[lane * WF + wc]);
    float2 t1 = unpackbf(sImg[(lane + 64) * WF + wc]);
    bufA[grp][lane]      = t0;
    bufA[grp][lane + 64] = t1;
    float2* R = fft128(bufA[grp], bufB[grp], tw, lane, 0);
    if (w < WF) {
      float2 a = R[lane], b = R[lane + 64];
      sImg[lane * WF + w]        = packbf(a.x, a.y);
      sImg[(lane + 64) * WF + w] = packbf(b.x, b.y);
    }
  }
  __syncthreads();

  const uint4* s4 = (const uint4*)sImg;
  uint4* d4 = (uint4*)dst;
  for (int idx = t; idx < NBIN / 4; idx += 256) d4[idx] = s4[idx];
}

// ---------------------------------------------------------------------------
// Spectral contraction via MFMA. Per bin p: C[o,b] = sum_i W'[o,k]*S[k,b]
// with K interleaved (k=2i+c): W'=[Wr,-Wi], S=[Sr,Si], S'=[Si,-Sr].
// Cr = W'.S ; Ci = W'.S'.
// Block: 16 bins x 32 o x 32 b. 4 waves = (o-half) x (bin-half).
// K staged in quarters (i-run 16 -> K=32 = one MFMA step).
// ---------------------------------------------------------------------------
__global__ __launch_bounds__(256) void spec_mm(const unsigned int* __restrict__ sf,
                                               const float* __restrict__ wr,
                                               const float* __restrict__ wi,
                                               unsigned int* __restrict__ of) {
  __shared__ unsigned int wbuf[16 * 32 * 16];   // [bin][o][i] words, 32 KB
  __shared__ unsigned int sbuf[16 * 32 * 16];   // [bin][b][i] words, 32 KB

  const int t = threadIdx.x;
  // T1 XCD swizzle: 2080 blocks = 8 * 260, bijective.
  const int bid = blockIdx.x;
  const int swz = (bid & 7) * 260 + (bid >> 3);
  const int o0 = (swz & 3) * 32;        // o-tile fastest -> same-XCD sig reuse
  const int p0 = (swz >> 2) * 16;

  const int l = t & 63, wv = t >> 6;
  const int bh = wv & 1, oh = wv >> 1;  // bin-half, o-half
  const int m16 = l & 15, q = l >> 4;

  f32x4 aR[8][2] = {};
  f32x4 aI[8][2] = {};

  for (int kq = 0; kq < 4; ++kq) {
    // ---- stage weights: [bin][o][i] <- pack(wr, -wi) ----
#pragma unroll
    for (int r = 0; r < 8; ++r) {
      const int lin = r * 256 + t;
      const int pq = lin & 3, i = (lin >> 2) & 15, o = lin >> 6;
      const size_t ga = ((size_t)(o0 + o) * CIN + kq * 16 + i) * NBIN + p0 + pq * 4;
      const float4 vr = *(const float4*)(wr + ga);
      const float4 vi = *(const float4*)(wi + ga);
      const int base = (pq * 4) * 512 + o * 16 + i;
      wbuf[base]        = packbf(vr.x, -vi.x);
      wbuf[base + 512]  = packbf(vr.y, -vi.y);
      wbuf[base + 1024] = packbf(vr.z, -vi.z);
      wbuf[base + 1536] = packbf(vr.w, -vi.w);
    }
    // ---- stage sig (raw u32 copy) ----
#pragma unroll
    for (int r = 0; r < 8; ++r) {
      const int lin = r * 256 + t;
      const int pq = lin & 3, i = (lin >> 2) & 15, b = lin >> 6;
      const size_t ga = ((size_t)b * CIN + kq * 16 + i) * NBIN + p0 + pq * 4;
      const uint4 v = *(const uint4*)(sf + ga);
      const int base = (pq * 4) * 512 + b * 16 + i;
      sbuf[base] = v.x; sbuf[base + 512] = v.y; sbuf[base + 1024] = v.z; sbuf[base + 1536] = v.w;
    }
    __syncthreads();

#pragma unroll
    for (int bin = 0; bin < 8; ++bin) {
      const int bg = bh * 8 + bin;
      const uint4 a = *(const uint4*)&wbuf[bg * 512 + (oh * 16 + m16) * 16 + q * 4];
#pragma unroll
      for (int nt = 0; nt < 2; ++nt) {
        const uint4 s  = *(const uint4*)&sbuf[bg * 512 + (nt * 16 + m16) * 16 + q * 4];
        const uint4 sp = derive(s);
        aR[bin][nt] = MFMA16(a, s,  aR[bin][nt]);
        aI[bin][nt] = MFMA16(a, sp, aI[bin][nt]);
      }
    }
    __syncthreads();
  }

  // ---- epilogue: lane assembles 8-bin (32B) runs, direct global stores ----
#pragma unroll
  for (int nt = 0; nt < 2; ++nt) {
    const int b = nt * 16 + m16;
#pragma unroll
    for (int r = 0; r < 4; ++r) {
      const int o = o0 + oh * 16 + q * 4 + r;
      uint4 lo, hi;
      lo.x = packbf(aR[0][nt][r], aI[0][nt][r]);
      lo.y = packbf(aR[1][nt][r], aI[1][nt][r]);
      lo.z = packbf(aR[2][nt][r], aI[2][nt][r]);
      lo.w = packbf(aR[3][nt][r], aI[3][nt][r]);
      hi.x = packbf(aR[4][nt][r], aI[4][nt][r]);
      hi.y = packbf(aR[5][nt][r], aI[5][nt][r]);
      hi.z = packbf(aR[6][nt][r], aI[6][nt][r]);
      hi.w = packbf(aR[7][nt][r], aI[7][nt][r]);
      const size_t ga = ((size_t)b * COUT + o) * NBIN + p0 + bh * 8;
      *(uint4*)(of + ga)     = lo;
      *(uint4*)(of + ga + 4) = hi;
    }
  }
}

// ---------------------------------------------------------------------------
// Inverse: one block per (b, o). packed bf16 128x65 -> real 120x120 (+bias).
// ---------------------------------------------------------------------------
__global__ __launch_bounds__(256) void inv_fft(const unsigned int* __restrict__ of,
                                               const float* __restrict__ bias,
                                               float* __restrict__ out) {
  __shared__ unsigned int sImg[NBIN];
  __shared__ float2 bufA[4][128];
  __shared__ float2 bufB[4][128];
  __shared__ float2 tw[64];

  const int t = threadIdx.x, grp = t >> 6, lane = t & 63;
  const size_t img = blockIdx.x;                 // b*COUT + o
  const unsigned int* src = of + img * (size_t)NBIN;
  float* dst = out + img * (size_t)(HO * WO);
  const float bo = bias[img & (COUT - 1)];

  if (t < 64) {
    float s_, c_;
    sincosf(-(float)M_PI * (float)t / 64.f, &s_, &c_);
    tw[t] = make_float2(c_, s_);
  }

  const uint4* s4 = (const uint4*)src;
  uint4* d4 = (uint4*)sImg;
  for (int idx = t; idx < NBIN / 4; idx += 256) d4[idx] = s4[idx];
  __syncthreads();

  // inverse complex FFT along H
  for (int batch = 0; batch < 17; ++batch) {
    const int w  = batch * 4 + grp;
    const int wc = (w < WF) ? w : (WF - 1);
    bufA[grp][lane]      = unpackbf(sImg[lane * WF + wc]);
    bufA[grp][lane + 64] = unpackbf(sImg[(lane + 64) * WF + wc]);
    float2* R = fft128(bufA[grp], bufB[grp], tw, lane, 1);
    if (w < WF) {
      float2 a = R[lane], b = R[lane + 64];
      sImg[lane * WF + w]        = packbf(a.x, a.y);
      sImg[(lane + 64) * WF + w] = packbf(b.x, b.y);
    }
  }
  __syncthreads();

  // irfft along W (pair trick), crop, scale, +bias
  const float scale = 1.f / 16384.f;
  for (int batch = 0; batch < 15; ++batch) {       // row pairs 0..59
    const int j = batch * 4 + grp;
    const unsigned int* X0p = &sImg[(size_t)(2 * j) * WF];
    const unsigned int* X1p = &sImg[(size_t)(2 * j + 1) * WF];
    float2 za, zb;
    if (lane == 0) {
      za = make_float2(unpackbf(X0p[0]).x,  unpackbf(X1p[0]).x);    // DC
      zb = make_float2(unpackbf(X0p[64]).x, unpackbf(X1p[64]).x);   // Nyquist
    } else {
      float2 x0 = unpackbf(X0p[lane]), x1 = unpackbf(X1p[lane]);
      za = make_float2(x0.x - x1.y, x0.y + x1.x);
      const int mI = 64 - lane;
      float2 y0 = unpackbf(X0p[mI]), y1 = unpackbf(X1p[mI]);
      zb = make_float2(y0.x + y1.y, y1.x - y0.y);
    }
    bufA[grp][lane]      = za;
    bufA[grp][lane + 64] = zb;
    float2* R = fft128(bufA[grp], bufB[grp], tw, lane, 1);
    float2 v0 = R[lane];
    dst[(size_t)(2 * j) * WO + lane]     = v0.x * scale + bo;
    dst[(size_t)(2 * j + 1) * WO + lane] = v0.y * scale + bo;
    if (lane < WO - 64) {
      float2 v1 = R[lane + 64];
      dst[(size_t)(2 * j) * WO + lane + 64]     = v1.x * scale + bo;
      dst[(size_t)(2 * j + 1) * WO + lane + 64] = v1.y * scale + bo;
    }
  }
}

// ---------------------------------------------------------------------------
extern "C" void kernel_launch(void* const* d_in, const int* in_sizes, int n_in,
                              void* d_out, int out_size, void* d_ws, size_t ws_size,
                              hipStream_t stream) {
  const float* signal = (const float*)d_in[0];
  const float* wr     = (const float*)d_in[1];
  const float* wi     = (const float*)d_in[2];
  const float* bias   = (const float*)d_in[3];
  float* out = (float*)d_out;

  // sig_fr bf16 (68.2 MB) in d_out[0,68.2) -- dead before inv writes output.
  // out_fr bf16 (136.3 MB) in d_ws.
  unsigned int* sig_fr = (unsigned int*)d_out;
  unsigned int* out_fr = (unsigned int*)d_ws;
  (void)in_sizes; (void)n_in; (void)out_size; (void)ws_size;

  fwd_fft<<<NB * CIN, 256, 0, stream>>>(signal, sig_fr);
  spec_mm<<<2080, 256, 0, stream>>>(sig_fr, wr, wi, out_fr);
  inv_fft<<<NB * COUT, 256, 0, stream>>>(out_fr, bias, out);
}

// Round 4
// 613.923 us; speedup vs baseline: 1.8632x; 1.4622x over previous
//
#include <hip/hip_runtime.h>
#include <math.h>

#define DI __device__ __forceinline__

constexpr int Hh   = 128;
constexpr int Ww   = 128;
constexpr int WF   = 65;            // W/2+1
constexpr int NBIN = Hh * WF;       // 8320
constexpr int NB   = 32;            // batch
constexpr int CIN  = 64;
constexpr int COUT = 128;
constexpr int HO   = 120;
constexpr int WO   = 120;

typedef __bf16 bf16x8 __attribute__((ext_vector_type(8)));
typedef float  f32x4  __attribute__((ext_vector_type(4)));

// ---- bf16 pack/unpack (RNE) ----
DI unsigned int bfbits(float x) {
  unsigned int u = __float_as_uint(x);
  return (u + 0x7FFFu + ((u >> 16) & 1u)) >> 16;
}
DI unsigned int packbf(float re, float im) { return bfbits(re) | (bfbits(im) << 16); }
DI float2 unpackbf(unsigned int v) {
  return make_float2(__uint_as_float(v << 16), __uint_as_float(v & 0xFFFF0000u));
}

DI f32x4 MFMA16(uint4 a, uint4 b, f32x4 c) {
  return __builtin_amdgcn_mfma_f32_16x16x32_bf16(
      __builtin_bit_cast(bf16x8, a), __builtin_bit_cast(bf16x8, b), c, 0, 0, 0);
}
// S=[Sr,Si] per u32 -> S'=[Si,-Sr]
DI unsigned int rotneg(unsigned int x) { return ((x << 16) | (x >> 16)) ^ 0x80000000u; }
DI uint4 derive(uint4 s) {
  uint4 r; r.x = rotneg(s.x); r.y = rotneg(s.y); r.z = rotneg(s.z); r.w = rotneg(s.w);
  return r;
}

// Wave-local LDS sync for the FFT ping-pong (one wave owns its buffers).
DI void wsync() {
  asm volatile("s_waitcnt lgkmcnt(0)" ::: "memory");
  __builtin_amdgcn_sched_barrier(0);
}

// ---------------------------------------------------------------------------
// 128-point radix-2 Stockham FFT in LDS, one wave per sequence.
// ---------------------------------------------------------------------------
DI float2* fft128(float2* s, float2* d, const float2* tw, int lane, int inv) {
  wsync();
#pragma unroll
  for (int st = 0; st < 7; ++st) {
    const int m  = 1 << st;
    const int tj = lane & ~(m - 1);
    float2 c0 = s[lane];
    float2 c1 = s[lane + 64];
    float2 w  = tw[tj];
    float  wy = inv ? -w.y : w.y;
    float  sx = c0.x + c1.x, sy = c0.y + c1.y;
    float  dx = c0.x - c1.x, dy = c0.y - c1.y;
    float2 wd = make_float2(w.x * dx - wy * dy, w.x * dy + wy * dx);
    const int di = lane + tj;
    d[di]     = make_float2(sx, sy);
    d[di + m] = wd;
    wsync();
    float2* t_ = s; s = d; d = t_;
  }
  return s;
}

// ---------------------------------------------------------------------------
// Forward: one block per (b, i). real 128x128 -> packed bf16 complex 128x65.
// ---------------------------------------------------------------------------
__global__ __launch_bounds__(256) void fwd_fft(const float* __restrict__ sig,
                                               unsigned int* __restrict__ sf) {
  __shared__ unsigned int sImg[NBIN];        // 33280 B, packed bf16 pairs
  __shared__ float2 bufA[4][128];
  __shared__ float2 bufB[4][128];
  __shared__ float2 tw[64];

  const int t = threadIdx.x, grp = t >> 6, lane = t & 63;
  const size_t img = blockIdx.x;
  const float* src = sig + img * (size_t)(Hh * Ww);
  unsigned int* dst = sf + img * (size_t)NBIN;

  if (t < 64) {
    float s_, c_;
    sincosf(-(float)M_PI * (float)t / 64.f, &s_, &c_);
    tw[t] = make_float2(c_, s_);
  }
  __syncthreads();

  // phase 1: row rfft (two real rows per complex FFT)
  for (int batch = 0; batch < 16; ++batch) {
    const int j = batch * 4 + grp;
    const float* r0 = src + (size_t)(2 * j) * Ww;
    bufA[grp][lane]      = make_float2(r0[lane],      r0[Ww + lane]);
    bufA[grp][lane + 64] = make_float2(r0[lane + 64], r0[Ww + lane + 64]);
    float2* Z = fft128(bufA[grp], bufB[grp], tw, lane, 0);
    float2 Zk = Z[lane];
    float2 Zm = Z[(128 - lane) & 127];
    sImg[(2 * j) * WF + lane]     = packbf(0.5f * (Zk.x + Zm.x), 0.5f * (Zk.y - Zm.y));
    sImg[(2 * j + 1) * WF + lane] = packbf(0.5f * (Zk.y + Zm.y), 0.5f * (Zm.x - Zk.x));
    if (lane == 0) {
      float2 Z64 = Z[64];
      sImg[(2 * j) * WF + 64]     = packbf(Z64.x, 0.f);
      sImg[(2 * j + 1) * WF + 64] = packbf(Z64.y, 0.f);
    }
  }
  __syncthreads();

  // phase 2: complex FFT along H, disjoint columns per group
  for (int batch = 0; batch < 17; ++batch) {
    const int w  = batch * 4 + grp;
    const int wc = (w < WF) ? w : (WF - 1);
    float2 t0 = unpackbf(sImg[lane * WF + wc]);
    float2 t1 = unpackbf(sImg[(lane + 64) * WF + wc]);
    bufA[grp][lane]      = t0;
    bufA[grp][lane + 64] = t1;
    float2* R = fft128(bufA[grp], bufB[grp], tw, lane, 0);
    if (w < WF) {
      float2 a = R[lane], b = R[lane + 64];
      sImg[lane * WF + w]        = packbf(a.x, a.y);
      sImg[(lane + 64) * WF + w] = packbf(b.x, b.y);
    }
  }
  __syncthreads();

  const uint4* s4 = (const uint4*)sImg;
  uint4* d4 = (uint4*)dst;
  for (int idx = t; idx < NBIN / 4; idx += 256) d4[idx] = s4[idx];
}

// ---------------------------------------------------------------------------
// Spectral contraction via MFMA. Per bin p: C[o,b] = sum_k W'[o,k]*S[k,b],
// K = 2*CIN interleaved (k=2i+c): W'=[Wr,-Wi], S=[Sr,Si], S'=[Si,-Sr];
// Cr = W'.S ; Ci = W'.S'.
//
// Block: 512 thr (8 waves = 2 o-frag x 4 bin-pairs). Tile: 8 bins x 32 o x 32 b.
// K staged in 4 chunks of 16 i. LDS 32 KB, XOR-swizzled (uint4-granular) so
// staging ds_write_b64 and fragment ds_read_b128 are <=2-way.
// T14: next chunk's global loads issued before the MFMA phase.
// ---------------------------------------------------------------------------
__global__ __launch_bounds__(512, 4) void spec_mm(const unsigned int* __restrict__ sf,
                                                  const float* __restrict__ wr,
                                                  const float* __restrict__ wi,
                                                  unsigned int* __restrict__ of) {
  __shared__ unsigned int wbuf[8 * 32 * 16];   // [p][o][i] words, swizzled, 16 KB
  __shared__ unsigned int sbuf[8 * 32 * 16];   // [p][b][i] words, swizzled, 16 KB

  const int t = threadIdx.x;
  // T1 XCD swizzle: 4160 blocks = 8 * 520, bijective. Same-XCD neighbors share
  // the p-range (sig L2 reuse) across the 4 o-tiles.
  const int bid = blockIdx.x;
  const int swz = (bid & 7) * 520 + (bid >> 3);
  const int o0 = (swz & 3) * 32;
  const int p0 = (swz >> 2) * 8;

  // ---- staging decomposition: one weight item + one sig item per thread ----
  const int ph  = t & 1;              // which float4 of the 8-bin p-row
  const int i2  = (t >> 1) & 7;       // i-pair index (i = 2*i2, 2*i2+1)
  const int row = (t >> 4) & 31;      // o for weights, b for sig
  const int i   = i2 * 2;
  const int q   = i2 >> 1;            // i-quad
  const int iw  = (i2 & 1) * 2;       // word offset within uint4

  const float* wrp = wr + ((size_t)(o0 + row) * CIN + i) * NBIN + p0 + ph * 4;
  const float* wip = wi + ((size_t)(o0 + row) * CIN + i) * NBIN + p0 + ph * 4;
  const unsigned int* sfp = sf + ((size_t)row * CIN + i) * NBIN + p0 + ph * 4;

  const int wbase = (((row * 4 + q) ^ ((row >> 1) & 3)) << 2) + iw;  // same for sbuf

  // ---- MFMA-phase decomposition ----
  const int l = t & 63, wv = t >> 6;
  const int oh = wv & 1, bh = wv >> 1;         // o-half, bin-pair
  const int m16 = l & 15, lq = l >> 4;
  const int orow = oh * 16 + m16;
  const int aoff  = (((orow * 4 + lq) ^ ((orow >> 1) & 3)) << 2);
  const int b0c = m16, b1c = 16 + m16;
  const int soff0 = (((b0c * 4 + lq) ^ ((b0c >> 1) & 3)) << 2);
  const int soff1 = (((b1c * 4 + lq) ^ ((b1c >> 1) & 3)) << 2);

  f32x4 aR[2][2] = {};
  f32x4 aI[2][2] = {};

  // ---- prologue: issue chunk-0 loads ----
  float4 vr0 = *(const float4*)wrp;
  float4 vr1 = *(const float4*)(wrp + NBIN);
  float4 vi0 = *(const float4*)wip;
  float4 vi1 = *(const float4*)(wip + NBIN);
  uint4  sv0 = *(const uint4*)sfp;
  uint4  sv1 = *(const uint4*)(sfp + NBIN);

  for (int kq = 0; kq < 4; ++kq) {
    // ---- pack current regs -> LDS (b64, 2-way max via swizzle) ----
    const float* r0 = (const float*)&vr0;
    const float* r1 = (const float*)&vr1;
    const float* q0 = (const float*)&vi0;
    const float* q1 = (const float*)&vi1;
    const unsigned int* u0 = (const unsigned int*)&sv0;
    const unsigned int* u1 = (const unsigned int*)&sv1;
#pragma unroll
    for (int j = 0; j < 4; ++j) {
      const int prow = (ph * 4 + j) * 512;
      uint2 wv2; wv2.x = packbf(r0[j], -q0[j]); wv2.y = packbf(r1[j], -q1[j]);
      *(uint2*)&wbuf[prow + wbase] = wv2;
      uint2 sv2; sv2.x = u0[j]; sv2.y = u1[j];
      *(uint2*)&sbuf[prow + wbase] = sv2;
    }
    __syncthreads();

    // ---- T14: issue next chunk's loads; latency hides under MFMA ----
    if (kq < 3) {
      const size_t adv = (size_t)(kq + 1) * 16 * NBIN;
      vr0 = *(const float4*)(wrp + adv);
      vr1 = *(const float4*)(wrp + adv + NBIN);
      vi0 = *(const float4*)(wip + adv);
      vi1 = *(const float4*)(wip + adv + NBIN);
      sv0 = *(const uint4*)(sfp + adv);
      sv1 = *(const uint4*)(sfp + adv + NBIN);
    }

    // ---- MFMA phase: 2 bins x 2 b-tiles x {R,I} = 8 MFMAs/wave ----
#pragma unroll
    for (int bin = 0; bin < 2; ++bin) {
      const int prow = (bh * 2 + bin) * 512;
      const uint4 a  = *(const uint4*)&wbuf[prow + aoff];
      const uint4 s0 = *(const uint4*)&sbuf[prow + soff0];
      const uint4 s1 = *(const uint4*)&sbuf[prow + soff1];
      const uint4 p0v = derive(s0);
      const uint4 p1v = derive(s1);
      aR[bin][0] = MFMA16(a, s0,  aR[bin][0]);
      aI[bin][0] = MFMA16(a, p0v, aI[bin][0]);
      aR[bin][1] = MFMA16(a, s1,  aR[bin][1]);
      aI[bin][1] = MFMA16(a, p1v, aI[bin][1]);
    }
    __syncthreads();
  }

  // ---- epilogue: 8B stores, 2 consecutive bins per (b,o) ----
#pragma unroll
  for (int nt = 0; nt < 2; ++nt) {
    const int b = nt * 16 + m16;
#pragma unroll
    for (int r = 0; r < 4; ++r) {
      const int o = o0 + oh * 16 + lq * 4 + r;
      uint2 v;
      v.x = packbf(aR[0][nt][r], aI[0][nt][r]);
      v.y = packbf(aR[1][nt][r], aI[1][nt][r]);
      *(uint2*)(of + ((size_t)b * COUT + o) * NBIN + p0 + bh * 2) = v;
    }
  }
}

// ---------------------------------------------------------------------------
// Inverse: one block per (b, o). packed bf16 128x65 -> real 120x120 (+bias).
// ---------------------------------------------------------------------------
__global__ __launch_bounds__(256) void inv_fft(const unsigned int* __restrict__ of,
                                               const float* __restrict__ bias,
                                               float* __restrict__ out) {
  __shared__ unsigned int sImg[NBIN];
  __shared__ float2 bufA[4][128];
  __shared__ float2 bufB[4][128];
  __shared__ float2 tw[64];

  const int t = threadIdx.x, grp = t >> 6, lane = t & 63;
  const size_t img = blockIdx.x;                 // b*COUT + o
  const unsigned int* src = of + img * (size_t)NBIN;
  float* dst = out + img * (size_t)(HO * WO);
  const float bo = bias[img & (COUT - 1)];

  if (t < 64) {
    float s_, c_;
    sincosf(-(float)M_PI * (float)t / 64.f, &s_, &c_);
    tw[t] = make_float2(c_, s_);
  }

  const uint4* s4 = (const uint4*)src;
  uint4* d4 = (uint4*)sImg;
  for (int idx = t; idx < NBIN / 4; idx += 256) d4[idx] = s4[idx];
  __syncthreads();

  // inverse complex FFT along H
  for (int batch = 0; batch < 17; ++batch) {
    const int w  = batch * 4 + grp;
    const int wc = (w < WF) ? w : (WF - 1);
    bufA[grp][lane]      = unpackbf(sImg[lane * WF + wc]);
    bufA[grp][lane + 64] = unpackbf(sImg[(lane + 64) * WF + wc]);
    float2* R = fft128(bufA[grp], bufB[grp], tw, lane, 1);
    if (w < WF) {
      float2 a = R[lane], b = R[lane + 64];
      sImg[lane * WF + w]        = packbf(a.x, a.y);
      sImg[(lane + 64) * WF + w] = packbf(b.x, b.y);
    }
  }
  __syncthreads();

  // irfft along W (pair trick), crop, scale, +bias
  const float scale = 1.f / 16384.f;
  for (int batch = 0; batch < 15; ++batch) {       // row pairs 0..59
    const int j = batch * 4 + grp;
    const unsigned int* X0p = &sImg[(size_t)(2 * j) * WF];
    const unsigned int* X1p = &sImg[(size_t)(2 * j + 1) * WF];
    float2 za, zb;
    if (lane == 0) {
      za = make_float2(unpackbf(X0p[0]).x,  unpackbf(X1p[0]).x);    // DC
      zb = make_float2(unpackbf(X0p[64]).x, unpackbf(X1p[64]).x);   // Nyquist
    } else {
      float2 x0 = unpackbf(X0p[lane]), x1 = unpackbf(X1p[lane]);
      za = make_float2(x0.x - x1.y, x0.y + x1.x);
      const int mI = 64 - lane;
      float2 y0 = unpackbf(X0p[mI]), y1 = unpackbf(X1p[mI]);
      zb = make_float2(y0.x + y1.y, y1.x - y0.y);
    }
    bufA[grp][lane]      = za;
    bufA[grp][lane + 64] = zb;
    float2* R = fft128(bufA[grp], bufB[grp], tw, lane, 1);
    float2 v0 = R[lane];
    dst[(size_t)(2 * j) * WO + lane]     = v0.x * scale + bo;
    dst[(size_t)(2 * j + 1) * WO + lane] = v0.y * scale + bo;
    if (lane < WO - 64) {
      float2 v1 = R[lane + 64];
      dst[(size_t)(2 * j) * WO + lane + 64]     = v1.x * scale + bo;
      dst[(size_t)(2 * j + 1) * WO + lane + 64] = v1.y * scale + bo;
    }
  }
}

// ---------------------------------------------------------------------------
extern "C" void kernel_launch(void* const* d_in, const int* in_sizes, int n_in,
                              void* d_out, int out_size, void* d_ws, size_t ws_size,
                              hipStream_t stream) {
  const float* signal = (const float*)d_in[0];
  const float* wr     = (const float*)d_in[1];
  const float* wi     = (const float*)d_in[2];
  const float* bias   = (const float*)d_in[3];
  float* out = (float*)d_out;

  // sig_fr bf16 (68.2 MB) in d_out -- dead before inv writes output.
  // out_fr bf16 (136.3 MB) in d_ws.
  unsigned int* sig_fr = (unsigned int*)d_out;
  unsigned int* out_fr = (unsigned int*)d_ws;
  (void)in_sizes; (void)n_in; (void)out_size; (void)ws_size;

  fwd_fft<<<NB * CIN, 256, 0, stream>>>(signal, sig_fr);
  spec_mm<<<4160, 512, 0, stream>>>(sig_fr, wr, wi, out_fr);
  inv_fft<<<NB * COUT, 256, 0, stream>>>(out_fr, bias, out);
}

// Round 5
// 599.092 us; speedup vs baseline: 1.9094x; 1.0248x over previous
//
#include <hip/hip_runtime.h>
#include <math.h>

#define DI __device__ __forceinline__

constexpr int Hh   = 128;
constexpr int Ww   = 128;
constexpr int WF   = 65;            // W/2+1
constexpr int NBIN = Hh * WF;       // 8320
constexpr int NB   = 32;            // batch
constexpr int CIN  = 64;
constexpr int COUT = 128;
constexpr int HO   = 120;
constexpr int WO   = 120;

typedef __bf16 bf16x8 __attribute__((ext_vector_type(8)));
typedef float  f32x4  __attribute__((ext_vector_type(4)));

// ---- bf16 pack/unpack (RNE) ----
DI unsigned int bfbits(float x) {
  unsigned int u = __float_as_uint(x);
  return (u + 0x7FFFu + ((u >> 16) & 1u)) >> 16;
}
DI unsigned int packbf(float re, float im) { return bfbits(re) | (bfbits(im) << 16); }
DI float2 unpackbf(unsigned int v) {
  return make_float2(__uint_as_float(v << 16), __uint_as_float(v & 0xFFFF0000u));
}

DI f32x4 MFMA16(uint4 a, uint4 b, f32x4 c) {
  return __builtin_amdgcn_mfma_f32_16x16x32_bf16(
      __builtin_bit_cast(bf16x8, a), __builtin_bit_cast(bf16x8, b), c, 0, 0, 0);
}
// S=[Sr,Si] per u32 -> S'=[Si,-Sr]
DI unsigned int rotneg(unsigned int x) { return ((x << 16) | (x >> 16)) ^ 0x80000000u; }
DI uint4 derive(uint4 s) {
  uint4 r; r.x = rotneg(s.x); r.y = rotneg(s.y); r.z = rotneg(s.z); r.w = rotneg(s.w);
  return r;
}

// Wave-local LDS sync for the FFT ping-pong (one wave owns its buffers).
DI void wsync() {
  asm volatile("s_waitcnt lgkmcnt(0)" ::: "memory");
  __builtin_amdgcn_sched_barrier(0);
}

// ---------------------------------------------------------------------------
// TWO independent 128-point radix-2 Stockham FFTs per wave (ILP-2): FFT0 at
// s[0..127], FFT1 at s[128..255]. One wsync per stage covers both.
// ---------------------------------------------------------------------------
DI float2* fft128x2(float2* s, float2* d, const float2* tw, int lane, int inv) {
  wsync();
#pragma unroll
  for (int st = 0; st < 7; ++st) {
    const int m  = 1 << st;
    const int tj = lane & ~(m - 1);
    float2 a0 = s[lane],       a1 = s[lane + 64];
    float2 b0 = s[lane + 128], b1 = s[lane + 192];
    float2 w  = tw[tj];
    const float wy = inv ? -w.y : w.y;
    const int di = lane + tj;
    {
      float sx = a0.x + a1.x, sy = a0.y + a1.y;
      float dx = a0.x - a1.x, dy = a0.y - a1.y;
      d[di]     = make_float2(sx, sy);
      d[di + m] = make_float2(w.x * dx - wy * dy, w.x * dy + wy * dx);
    }
    {
      float sx = b0.x + b1.x, sy = b0.y + b1.y;
      float dx = b0.x - b1.x, dy = b0.y - b1.y;
      d[di + 128]     = make_float2(sx, sy);
      d[di + 128 + m] = make_float2(w.x * dx - wy * dy, w.x * dy + wy * dx);
    }
    wsync();
    float2* t_ = s; s = d; d = t_;
  }
  return s;
}

// ---------------------------------------------------------------------------
// Forward: one block per (b, i). real 128x128 -> packed bf16 complex 128x65.
// ---------------------------------------------------------------------------
__global__ __launch_bounds__(256) void fwd_fft(const float* __restrict__ sig,
                                               unsigned int* __restrict__ sf) {
  __shared__ unsigned int sImg[NBIN];        // 33280 B
  __shared__ float2 bufA[4][256];
  __shared__ float2 bufB[4][256];
  __shared__ float2 tw[64];

  const int t = threadIdx.x, grp = t >> 6, lane = t & 63;
  const size_t img = blockIdx.x;
  const float* src = sig + img * (size_t)(Hh * Ww);
  unsigned int* dst = sf + img * (size_t)NBIN;

  if (t < 64) {
    float s_, c_;
    sincosf(-(float)M_PI * (float)t / 64.f, &s_, &c_);
    tw[t] = make_float2(c_, s_);
  }
  __syncthreads();

  // phase 1: row rfft, 2 row-pairs per wave per batch (ILP-2)
  for (int batch = 0; batch < 8; ++batch) {
#pragma unroll
    for (int f = 0; f < 2; ++f) {
      const int jp = batch * 8 + grp * 2 + f;        // row pair 0..63
      const float* r0 = src + (size_t)(2 * jp) * Ww;
      bufA[grp][f * 128 + lane]      = make_float2(r0[lane],      r0[Ww + lane]);
      bufA[grp][f * 128 + 64 + lane] = make_float2(r0[lane + 64], r0[Ww + lane + 64]);
    }
    float2* Z = fft128x2(bufA[grp], bufB[grp], tw, lane, 0);
#pragma unroll
    for (int f = 0; f < 2; ++f) {
      const int jp = batch * 8 + grp * 2 + f;
      float2 Zk = Z[f * 128 + lane];
      float2 Zm = Z[f * 128 + ((128 - lane) & 127)];
      sImg[(2 * jp) * WF + lane]     = packbf(0.5f * (Zk.x + Zm.x), 0.5f * (Zk.y - Zm.y));
      sImg[(2 * jp + 1) * WF + lane] = packbf(0.5f * (Zk.y + Zm.y), 0.5f * (Zm.x - Zk.x));
      if (lane == 0) {
        float2 Z64 = Z[f * 128 + 64];
        sImg[(2 * jp) * WF + 64]     = packbf(Z64.x, 0.f);
        sImg[(2 * jp + 1) * WF + 64] = packbf(Z64.y, 0.f);
      }
    }
  }
  __syncthreads();

  // phase 2: complex FFT along H, 2 columns per wave per batch
  for (int batch = 0; batch < 9; ++batch) {
#pragma unroll
    for (int f = 0; f < 2; ++f) {
      const int w  = batch * 8 + grp * 2 + f;
      const int wc = (w < WF) ? w : (WF - 1);
      bufA[grp][f * 128 + lane]      = unpackbf(sImg[lane * WF + wc]);
      bufA[grp][f * 128 + 64 + lane] = unpackbf(sImg[(lane + 64) * WF + wc]);
    }
    float2* R = fft128x2(bufA[grp], bufB[grp], tw, lane, 0);
#pragma unroll
    for (int f = 0; f < 2; ++f) {
      const int w = batch * 8 + grp * 2 + f;
      if (w < WF) {
        float2 a = R[f * 128 + lane], b = R[f * 128 + 64 + lane];
        sImg[lane * WF + w]        = packbf(a.x, a.y);
        sImg[(lane + 64) * WF + w] = packbf(b.x, b.y);
      }
    }
  }
  __syncthreads();

  const uint4* s4 = (const uint4*)sImg;
  uint4* d4 = (uint4*)dst;
  for (int idx = t; idx < NBIN / 4; idx += 256) d4[idx] = s4[idx];
}

// ---------------------------------------------------------------------------
// Spectral contraction via MFMA. Per bin p: C[o,b] = sum_k W'[o,k]*S[k,b],
// K = 2*CIN interleaved: W'=[Wr,-Wi], S=[Sr,Si], S'=[Si,-Sr];
// Cr = W'.S ; Ci = W'.S'.
// Block: 512 thr (8 waves). Tile: 8 bins x 32 o x 32 b. K in 4 chunks of 16 i.
// Double-buffered LDS (2x32KB) + 2-chunk-deep register prefetch; one barrier
// per chunk. XOR-swizzled layout keeps ds ops <=2-way.
// ---------------------------------------------------------------------------
struct Chunk { float4 vr0, vr1, vi0, vi1; uint4 sv0, sv1; };

__global__ __launch_bounds__(512, 2) void spec_mm(const unsigned int* __restrict__ sf,
                                                  const float* __restrict__ wr,
                                                  const float* __restrict__ wi,
                                                  unsigned int* __restrict__ of) {
  __shared__ unsigned int wbuf[2][4096];   // [buf][p][o][i] swizzled, 16 KB each
  __shared__ unsigned int sbuf[2][4096];

  const int t = threadIdx.x;
  // T1 XCD swizzle: 4160 = 8*520, bijective; same-XCD neighbors = adjacent p.
  const int bid = blockIdx.x;
  const int swz = (bid & 7) * 520 + (bid >> 3);
  const int o0 = (swz & 3) * 32;
  const int p0 = (swz >> 2) * 8;

  // staging decomposition
  const int ph  = t & 1;
  const int i2  = (t >> 1) & 7;
  const int row = (t >> 4) & 31;
  const int i   = i2 * 2;
  const int q   = i2 >> 1;
  const int iw  = (i2 & 1) * 2;

  const float* wrp = wr + ((size_t)(o0 + row) * CIN + i) * NBIN + p0 + ph * 4;
  const float* wip = wi + ((size_t)(o0 + row) * CIN + i) * NBIN + p0 + ph * 4;
  const unsigned int* sfp = sf + ((size_t)row * CIN + i) * NBIN + p0 + ph * 4;

  const int wbase = (((row * 4 + q) ^ ((row >> 1) & 3)) << 2) + iw;

  // MFMA decomposition
  const int l = t & 63, wv = t >> 6;
  const int oh = wv & 1, bh = wv >> 1;
  const int m16 = l & 15, lq = l >> 4;
  const int orow = oh * 16 + m16;
  const int aoff  = (((orow * 4 + lq) ^ ((orow >> 1) & 3)) << 2);
  const int soff0 = (((m16 * 4 + lq) ^ ((m16 >> 1) & 3)) << 2);
  const int b1c = 16 + m16;
  const int soff1 = (((b1c * 4 + lq) ^ ((b1c >> 1) & 3)) << 2);

  f32x4 aR[2][2] = {};
  f32x4 aI[2][2] = {};

  auto loadC = [&](size_t adv) {
    Chunk c;
    c.vr0 = *(const float4*)(wrp + adv);
    c.vr1 = *(const float4*)(wrp + adv + NBIN);
    c.vi0 = *(const float4*)(wip + adv);
    c.vi1 = *(const float4*)(wip + adv + NBIN);
    c.sv0 = *(const uint4*)(sfp + adv);
    c.sv1 = *(const uint4*)(sfp + adv + NBIN);
    return c;
  };
  auto packC = [&](const Chunk& c, int buf) {
    const float* r0 = (const float*)&c.vr0;
    const float* r1 = (const float*)&c.vr1;
    const float* q0 = (const float*)&c.vi0;
    const float* q1 = (const float*)&c.vi1;
    const unsigned int* u0 = (const unsigned int*)&c.sv0;
    const unsigned int* u1 = (const unsigned int*)&c.sv1;
#pragma unroll
    for (int j = 0; j < 4; ++j) {
      const int prow = (ph * 4 + j) * 512;
      uint2 w2; w2.x = packbf(r0[j], -q0[j]); w2.y = packbf(r1[j], -q1[j]);
      *(uint2*)&wbuf[buf][prow + wbase] = w2;
      uint2 s2; s2.x = u0[j]; s2.y = u1[j];
      *(uint2*)&sbuf[buf][prow + wbase] = s2;
    }
  };
  auto mfmaPhase = [&](int buf) {
#pragma unroll
    for (int bin = 0; bin < 2; ++bin) {
      const int prow = (bh * 2 + bin) * 512;
      const uint4 a  = *(const uint4*)&wbuf[buf][prow + aoff];
      const uint4 s0 = *(const uint4*)&sbuf[buf][prow + soff0];
      const uint4 s1 = *(const uint4*)&sbuf[buf][prow + soff1];
      const uint4 p0v = derive(s0);
      const uint4 p1v = derive(s1);
      aR[bin][0] = MFMA16(a, s0,  aR[bin][0]);
      aI[bin][0] = MFMA16(a, p0v, aI[bin][0]);
      aR[bin][1] = MFMA16(a, s1,  aR[bin][1]);
      aI[bin][1] = MFMA16(a, p1v, aI[bin][1]);
    }
  };

  // pipeline: 2-chunk-deep prefetch, double-buffered LDS, 1 barrier/chunk
  Chunk ca = loadC(0);
  Chunk cb = loadC((size_t)16 * NBIN);
  packC(ca, 0);
  __syncthreads();

  ca = loadC((size_t)32 * NBIN);    // chunk 2
  mfmaPhase(0);
  packC(cb, 1);
  __syncthreads();

  cb = loadC((size_t)48 * NBIN);    // chunk 3
  mfmaPhase(1);
  packC(ca, 0);
  __syncthreads();

  mfmaPhase(0);
  packC(cb, 1);
  __syncthreads();

  mfmaPhase(1);

  // epilogue: 8B stores, 2 consecutive bins per (b,o)
#pragma unroll
  for (int nt = 0; nt < 2; ++nt) {
    const int b = nt * 16 + m16;
#pragma unroll
    for (int r = 0; r < 4; ++r) {
      const int o = o0 + oh * 16 + lq * 4 + r;
      uint2 v;
      v.x = packbf(aR[0][nt][r], aI[0][nt][r]);
      v.y = packbf(aR[1][nt][r], aI[1][nt][r]);
      *(uint2*)(of + ((size_t)b * COUT + o) * NBIN + p0 + bh * 2) = v;
    }
  }
}

// ---------------------------------------------------------------------------
// Inverse: one block per (b, o). packed bf16 128x65 -> real 120x120 (+bias).
// ---------------------------------------------------------------------------
__global__ __launch_bounds__(256) void inv_fft(const unsigned int* __restrict__ of,
                                               const float* __restrict__ bias,
                                               float* __restrict__ out) {
  __shared__ unsigned int sImg[NBIN];
  __shared__ float2 bufA[4][256];
  __shared__ float2 bufB[4][256];
  __shared__ float2 tw[64];

  const int t = threadIdx.x, grp = t >> 6, lane = t & 63;
  const size_t img = blockIdx.x;                 // b*COUT + o
  const unsigned int* src = of + img * (size_t)NBIN;
  float* dst = out + img * (size_t)(HO * WO);
  const float bo = bias[img & (COUT - 1)];

  if (t < 64) {
    float s_, c_;
    sincosf(-(float)M_PI * (float)t / 64.f, &s_, &c_);
    tw[t] = make_float2(c_, s_);
  }

  const uint4* s4 = (const uint4*)src;
  uint4* d4 = (uint4*)sImg;
  for (int idx = t; idx < NBIN / 4; idx += 256) d4[idx] = s4[idx];
  __syncthreads();

  // inverse complex FFT along H, 2 columns per wave per batch
  for (int batch = 0; batch < 9; ++batch) {
#pragma unroll
    for (int f = 0; f < 2; ++f) {
      const int w  = batch * 8 + grp * 2 + f;
      const int wc = (w < WF) ? w : (WF - 1);
      bufA[grp][f * 128 + lane]      = unpackbf(sImg[lane * WF + wc]);
      bufA[grp][f * 128 + 64 + lane] = unpackbf(sImg[(lane + 64) * WF + wc]);
    }
    float2* R = fft128x2(bufA[grp], bufB[grp], tw, lane, 1);
#pragma unroll
    for (int f = 0; f < 2; ++f) {
      const int w = batch * 8 + grp * 2 + f;
      if (w < WF) {
        float2 a = R[f * 128 + lane], b = R[f * 128 + 64 + lane];
        sImg[lane * WF + w]        = packbf(a.x, a.y);
        sImg[(lane + 64) * WF + w] = packbf(b.x, b.y);
      }
    }
  }
  __syncthreads();

  // irfft along W (pair trick), 2 row-pairs per wave per batch; crop+bias
  const float scale = 1.f / 16384.f;
  for (int batch = 0; batch < 8; ++batch) {        // row pairs 0..59 (+4 pad)
#pragma unroll
    for (int f = 0; f < 2; ++f) {
      const int jp = batch * 8 + grp * 2 + f;
      const int jc = (jp < 60) ? jp : 59;
      const unsigned int* X0p = &sImg[(size_t)(2 * jc) * WF];
      const unsigned int* X1p = X0p + WF;
      float2 za, zb;
      if (lane == 0) {
        za = make_float2(unpackbf(X0p[0]).x,  unpackbf(X1p[0]).x);    // DC
        zb = make_float2(unpackbf(X0p[64]).x, unpackbf(X1p[64]).x);   // Nyquist
      } else {
        float2 x0 = unpackbf(X0p[lane]), x1 = unpackbf(X1p[lane]);
        za = make_float2(x0.x - x1.y, x0.y + x1.x);
        const int mI = 64 - lane;
        float2 y0 = unpackbf(X0p[mI]), y1 = unpackbf(X1p[mI]);
        zb = make_float2(y0.x + y1.y, y1.x - y0.y);
      }
      bufA[grp][f * 128 + lane]      = za;
      bufA[grp][f * 128 + 64 + lane] = zb;
    }
    float2* R = fft128x2(bufA[grp], bufB[grp], tw, lane, 1);
#pragma unroll
    for (int f = 0; f < 2; ++f) {
      const int jp = batch * 8 + grp * 2 + f;
      if (jp < 60) {
        float2 v0 = R[f * 128 + lane];
        dst[(size_t)(2 * jp) * WO + lane]     = v0.x * scale + bo;
        dst[(size_t)(2 * jp + 1) * WO + lane] = v0.y * scale + bo;
        if (lane < WO - 64) {
          float2 v1 = R[f * 128 + 64 + lane];
          dst[(size_t)(2 * jp) * WO + lane + 64]     = v1.x * scale + bo;
          dst[(size_t)(2 * jp + 1) * WO + lane + 64] = v1.y * scale + bo;
        }
      }
    }
  }
}

// ---------------------------------------------------------------------------
extern "C" void kernel_launch(void* const* d_in, const int* in_sizes, int n_in,
                              void* d_out, int out_size, void* d_ws, size_t ws_size,
                              hipStream_t stream) {
  const float* signal = (const float*)d_in[0];
  const float* wr     = (const float*)d_in[1];
  const float* wi     = (const float*)d_in[2];
  const float* bias   = (const float*)d_in[3];
  float* out = (float*)d_out;

  unsigned int* sig_fr = (unsigned int*)d_out;   // 68.2 MB, dead before inv writes
  unsigned int* out_fr = (unsigned int*)d_ws;    // 136.3 MB
  (void)in_sizes; (void)n_in; (void)out_size; (void)ws_size;

  fwd_fft<<<NB * CIN, 256, 0, stream>>>(signal, sig_fr);
  spec_mm<<<4160, 512, 0, stream>>>(sig_fr, wr, wi, out_fr);
  inv_fft<<<NB * COUT, 256, 0, stream>>>(out_fr, bias, out);
}

// Round 6
// 546.700 us; speedup vs baseline: 2.0923x; 1.0958x over previous
//
#include <hip/hip_runtime.h>
#include <math.h>

#define DI __device__ __forceinline__

constexpr int Hh   = 128;
constexpr int Ww   = 128;
constexpr int WF   = 65;            // W/2+1
constexpr int NBIN = Hh * WF;       // 8320
constexpr int NB   = 32;            // batch
constexpr int CIN  = 64;
constexpr int COUT = 128;
constexpr int HO   = 120;
constexpr int WO   = 120;

typedef __bf16 bf16x8 __attribute__((ext_vector_type(8)));
typedef float  f32x16 __attribute__((ext_vector_type(16)));

// ---- bf16 pack/unpack (RNE) ----
DI unsigned int bfbits(float x) {
  unsigned int u = __float_as_uint(x);
  return (u + 0x7FFFu + ((u >> 16) & 1u)) >> 16;
}
DI unsigned int packbf(float re, float im) { return bfbits(re) | (bfbits(im) << 16); }
DI float2 unpackbf(unsigned int v) {
  return make_float2(__uint_as_float(v << 16), __uint_as_float(v & 0xFFFF0000u));
}

DI f32x16 MFMA32(uint4 a, uint4 b, f32x16 c) {
  return __builtin_amdgcn_mfma_f32_32x32x16_bf16(
      __builtin_bit_cast(bf16x8, a), __builtin_bit_cast(bf16x8, b), c, 0, 0, 0);
}
// S=[Sr,Si] per u32 -> S'=[Si,-Sr]
DI unsigned int rotneg(unsigned int x) { return ((x << 16) | (x >> 16)) ^ 0x80000000u; }
DI uint4 derive(uint4 s) {
  uint4 r; r.x = rotneg(s.x); r.y = rotneg(s.y); r.z = rotneg(s.z); r.w = rotneg(s.w);
  return r;
}

// Wave-local LDS sync for the FFT ping-pong (one wave owns its buffers).
DI void wsync() {
  asm volatile("s_waitcnt lgkmcnt(0)" ::: "memory");
  __builtin_amdgcn_sched_barrier(0);
}

// ---------------------------------------------------------------------------
// TWO independent 128-point radix-2 Stockham FFTs per wave (ILP-2).
// ---------------------------------------------------------------------------
DI float2* fft128x2(float2* s, float2* d, const float2* tw, int lane, int inv) {
  wsync();
#pragma unroll
  for (int st = 0; st < 7; ++st) {
    const int m  = 1 << st;
    const int tj = lane & ~(m - 1);
    float2 a0 = s[lane],       a1 = s[lane + 64];
    float2 b0 = s[lane + 128], b1 = s[lane + 192];
    float2 w  = tw[tj];
    const float wy = inv ? -w.y : w.y;
    const int di = lane + tj;
    {
      float sx = a0.x + a1.x, sy = a0.y + a1.y;
      float dx = a0.x - a1.x, dy = a0.y - a1.y;
      d[di]     = make_float2(sx, sy);
      d[di + m] = make_float2(w.x * dx - wy * dy, w.x * dy + wy * dx);
    }
    {
      float sx = b0.x + b1.x, sy = b0.y + b1.y;
      float dx = b0.x - b1.x, dy = b0.y - b1.y;
      d[di + 128]     = make_float2(sx, sy);
      d[di + 128 + m] = make_float2(w.x * dx - wy * dy, w.x * dy + wy * dx);
    }
    wsync();
    float2* t_ = s; s = d; d = t_;
  }
  return s;
}

// ---------------------------------------------------------------------------
// Forward: one block per (b, i). real 128x128 -> packed bf16 complex 128x65.
// ---------------------------------------------------------------------------
__global__ __launch_bounds__(256) void fwd_fft(const float* __restrict__ sig,
                                               unsigned int* __restrict__ sf) {
  __shared__ unsigned int sImg[NBIN];        // 33280 B
  __shared__ float2 bufA[4][256];
  __shared__ float2 bufB[4][256];
  __shared__ float2 tw[64];

  const int t = threadIdx.x, grp = t >> 6, lane = t & 63;
  const size_t img = blockIdx.x;
  const float* src = sig + img * (size_t)(Hh * Ww);
  unsigned int* dst = sf + img * (size_t)NBIN;

  if (t < 64) {
    float s_, c_;
    sincosf(-(float)M_PI * (float)t / 64.f, &s_, &c_);
    tw[t] = make_float2(c_, s_);
  }
  __syncthreads();

  // phase 1: row rfft, 2 row-pairs per wave per batch (ILP-2)
  for (int batch = 0; batch < 8; ++batch) {
#pragma unroll
    for (int f = 0; f < 2; ++f) {
      const int jp = batch * 8 + grp * 2 + f;        // row pair 0..63
      const float* r0 = src + (size_t)(2 * jp) * Ww;
      bufA[grp][f * 128 + lane]      = make_float2(r0[lane],      r0[Ww + lane]);
      bufA[grp][f * 128 + 64 + lane] = make_float2(r0[lane + 64], r0[Ww + lane + 64]);
    }
    float2* Z = fft128x2(bufA[grp], bufB[grp], tw, lane, 0);
#pragma unroll
    for (int f = 0; f < 2; ++f) {
      const int jp = batch * 8 + grp * 2 + f;
      float2 Zk = Z[f * 128 + lane];
      float2 Zm = Z[f * 128 + ((128 - lane) & 127)];
      sImg[(2 * jp) * WF + lane]     = packbf(0.5f * (Zk.x + Zm.x), 0.5f * (Zk.y - Zm.y));
      sImg[(2 * jp + 1) * WF + lane] = packbf(0.5f * (Zk.y + Zm.y), 0.5f * (Zm.x - Zk.x));
      if (lane == 0) {
        float2 Z64 = Z[f * 128 + 64];
        sImg[(2 * jp) * WF + 64]     = packbf(Z64.x, 0.f);
        sImg[(2 * jp + 1) * WF + 64] = packbf(Z64.y, 0.f);
      }
    }
  }
  __syncthreads();

  // phase 2: complex FFT along H, 2 columns per wave per batch
  for (int batch = 0; batch < 9; ++batch) {
#pragma unroll
    for (int f = 0; f < 2; ++f) {
      const int w  = batch * 8 + grp * 2 + f;
      const int wc = (w < WF) ? w : (WF - 1);
      bufA[grp][f * 128 + lane]      = unpackbf(sImg[lane * WF + wc]);
      bufA[grp][f * 128 + 64 + lane] = unpackbf(sImg[(lane + 64) * WF + wc]);
    }
    float2* R = fft128x2(bufA[grp], bufB[grp], tw, lane, 0);
#pragma unroll
    for (int f = 0; f < 2; ++f) {
      const int w = batch * 8 + grp * 2 + f;
      if (w < WF) {
        float2 a = R[f * 128 + lane], b = R[f * 128 + 64 + lane];
        sImg[lane * WF + w]        = packbf(a.x, a.y);
        sImg[(lane + 64) * WF + w] = packbf(b.x, b.y);
      }
    }
  }
  __syncthreads();

  const uint4* s4 = (const uint4*)sImg;
  uint4* d4 = (uint4*)dst;
  for (int idx = t; idx < NBIN / 4; idx += 256) d4[idx] = s4[idx];
}

// ---------------------------------------------------------------------------
// Spectral contraction via 32x32x16 MFMA. Per bin p: C[o,b] = sum_k W'[o,k]S[k,b]
// K = 2*CIN interleaved: W'=[Wr,-Wi], S=[Sr,Si], S'=[Si,-Sr]; Cr=W'.S, Ci=W'.S'.
// Tile: 16 bins x 32 o x 32 b; 512 thr (8 waves, wave = 2 bins); 8 chunks of 8 i.
// LDS 16 planes x 260 words x 2 bufs = 33 KB; slot swizzle keeps <=4-way.
// ---------------------------------------------------------------------------
constexpr int PT    = 16;      // bins per block
constexpr int PLANE = 260;     // words per plane: 256 slots + 4 pad (bank rotate)

__global__ __launch_bounds__(512, 4) void spec_mm(const unsigned int* __restrict__ sf,
                                                  const float* __restrict__ wr,
                                                  const float* __restrict__ wi,
                                                  unsigned int* __restrict__ of) {
  __shared__ unsigned int wbuf[PT * PLANE];   // [p][slot(o,i)] 16.6 KB
  __shared__ unsigned int sbuf[PT * PLANE];   // [p][slot(b,i)]

  const int t = threadIdx.x;
  // XCD swizzle: 2080 = 8*260, bijective; same-XCD = contiguous p, o fastest.
  const int bid = blockIdx.x;
  const int swz = (bid & 7) * 260 + (bid >> 3);
  const int o0 = (swz & 3) * 32;
  const int p0 = (swz >> 2) * PT;

  // ---- staging map: 4 lanes (po) cover one 64-B line per (row, i) ----
  const int po = t & 3;              // p-quad (16 B)
  const int ii = (t >> 2) & 7;       // i within 8-i chunk
  const int rl = (t >> 5) & 15;      // row (o or b); also row+16

  const float* wrp0 = wr + ((size_t)(o0 + rl) * CIN + ii) * NBIN + p0 + po * 4;
  const float* wip0 = wi + ((size_t)(o0 + rl) * CIN + ii) * NBIN + p0 + po * 4;
  const unsigned int* sfp0 = sf + ((size_t)rl * CIN + ii) * NBIN + p0 + po * 4;
  const size_t rowAdv = (size_t)16 * CIN * NBIN;    // +16 rows

  // LDS slot for (row, i): quad = (row*2 + i/4) ^ ((row>>2)&7), word = quad*4 + i%4
  auto slotOf = [](int row, int i) {
    return ((((row * 2) + (i >> 2)) ^ ((row >> 2) & 7)) << 2) + (i & 3);
  };
  const int slotLo = slotOf(rl, ii);
  const int slotHi = slotOf(rl + 16, ii);

  // ---- MFMA map: wave = 2 bins; lane: row/col = l&31, i-quad = l>>5 ----
  const int l = t & 63, wv = t >> 6;
  const int lr = l & 31, lq = l >> 5;
  const int moff = ((((lr * 2) + lq) ^ ((lr >> 2) & 7)) << 2);
  const int pA = 2 * wv, pB = 2 * wv + 1;

  f32x16 aR0 = {}, aI0 = {}, aR1 = {}, aI1 = {};

  float4 w0r, w1r, w0i, w1i; uint4 s0v, s1v;
  {
    w0r = *(const float4*)(wrp0);          w1r = *(const float4*)(wrp0 + rowAdv);
    w0i = *(const float4*)(wip0);          w1i = *(const float4*)(wip0 + rowAdv);
    s0v = *(const uint4*)(sfp0);           s1v = *(const uint4*)(sfp0 + rowAdv);
  }

  for (int kq = 0; kq < 8; ++kq) {
    // ---- pack current chunk regs -> LDS ----
    const float* a0 = (const float*)&w0r;  const float* a1 = (const float*)&w1r;
    const float* b0 = (const float*)&w0i;  const float* b1 = (const float*)&w1i;
    const unsigned int* u0 = (const unsigned int*)&s0v;
    const unsigned int* u1 = (const unsigned int*)&s1v;
#pragma unroll
    for (int j = 0; j < 4; ++j) {
      const int pp = (po * 4 + j) * PLANE;
      wbuf[pp + slotLo] = packbf(a0[j], -b0[j]);
      wbuf[pp + slotHi] = packbf(a1[j], -b1[j]);
      sbuf[pp + slotLo] = u0[j];
      sbuf[pp + slotHi] = u1[j];
    }
    // ---- issue next chunk's loads before the barrier (latency hiding) ----
    if (kq < 7) {
      const size_t adv = (size_t)(kq + 1) * 8 * NBIN;
      w0r = *(const float4*)(wrp0 + adv);          w1r = *(const float4*)(wrp0 + adv + rowAdv);
      w0i = *(const float4*)(wip0 + adv);          w1i = *(const float4*)(wip0 + adv + rowAdv);
      s0v = *(const uint4*)(sfp0 + adv);           s1v = *(const uint4*)(sfp0 + adv + rowAdv);
    }
    __syncthreads();

    // ---- MFMA: 2 bins x {R,I} ----
    {
      const uint4 a  = *(const uint4*)&wbuf[pA * PLANE + moff];
      const uint4 s  = *(const uint4*)&sbuf[pA * PLANE + moff];
      aR0 = MFMA32(a, s, aR0);
      aI0 = MFMA32(a, derive(s), aI0);
    }
    {
      const uint4 a  = *(const uint4*)&wbuf[pB * PLANE + moff];
      const uint4 s  = *(const uint4*)&sbuf[pB * PLANE + moff];
      aR1 = MFMA32(a, s, aR1);
      aI1 = MFMA32(a, derive(s), aI1);
    }
    __syncthreads();
  }

  // ---- epilogue: uint2 (2 consecutive bins) per (b, o) ----
  const int b = lr;
#pragma unroll
  for (int r = 0; r < 16; ++r) {
    const int o = o0 + (r & 3) + 8 * (r >> 2) + 4 * lq;
    uint2 v;
    v.x = packbf(aR0[r], aI0[r]);
    v.y = packbf(aR1[r], aI1[r]);
    *(uint2*)(of + ((size_t)b * COUT + o) * NBIN + p0 + 2 * wv) = v;
  }
}

// ---------------------------------------------------------------------------
// Inverse: one block per (b, o). packed bf16 128x65 -> real 120x120 (+bias).
// ---------------------------------------------------------------------------
__global__ __launch_bounds__(256) void inv_fft(const unsigned int* __restrict__ of,
                                               const float* __restrict__ bias,
                                               float* __restrict__ out) {
  __shared__ unsigned int sImg[NBIN];
  __shared__ float2 bufA[4][256];
  __shared__ float2 bufB[4][256];
  __shared__ float2 tw[64];

  const int t = threadIdx.x, grp = t >> 6, lane = t & 63;
  const size_t img = blockIdx.x;                 // b*COUT + o
  const unsigned int* src = of + img * (size_t)NBIN;
  float* dst = out + img * (size_t)(HO * WO);
  const float bo = bias[img & (COUT - 1)];

  if (t < 64) {
    float s_, c_;
    sincosf(-(float)M_PI * (float)t / 64.f, &s_, &c_);
    tw[t] = make_float2(c_, s_);
  }

  const uint4* s4 = (const uint4*)src;
  uint4* d4 = (uint4*)sImg;
  for (int idx = t; idx < NBIN / 4; idx += 256) d4[idx] = s4[idx];
  __syncthreads();

  // inverse complex FFT along H, 2 columns per wave per batch
  for (int batch = 0; batch < 9; ++batch) {
#pragma unroll
    for (int f = 0; f < 2; ++f) {
      const int w  = batch * 8 + grp * 2 + f;
      const int wc = (w < WF) ? w : (WF - 1);
      bufA[grp][f * 128 + lane]      = unpackbf(sImg[lane * WF + wc]);
      bufA[grp][f * 128 + 64 + lane] = unpackbf(sImg[(lane + 64) * WF + wc]);
    }
    float2* R = fft128x2(bufA[grp], bufB[grp], tw, lane, 1);
#pragma unroll
    for (int f = 0; f < 2; ++f) {
      const int w = batch * 8 + grp * 2 + f;
      if (w < WF) {
        float2 a = R[f * 128 + lane], b = R[f * 128 + 64 + lane];
        sImg[lane * WF + w]        = packbf(a.x, a.y);
        sImg[(lane + 64) * WF + w] = packbf(b.x, b.y);
      }
    }
  }
  __syncthreads();

  // irfft along W (pair trick), 2 row-pairs per wave per batch; crop+bias
  const float scale = 1.f / 16384.f;
  for (int batch = 0; batch < 8; ++batch) {        // row pairs 0..59 (+4 pad)
#pragma unroll
    for (int f = 0; f < 2; ++f) {
      const int jp = batch * 8 + grp * 2 + f;
      const int jc = (jp < 60) ? jp : 59;
      const unsigned int* X0p = &sImg[(size_t)(2 * jc) * WF];
      const unsigned int* X1p = X0p + WF;
      float2 za, zb;
      if (lane == 0) {
        za = make_float2(unpackbf(X0p[0]).x,  unpackbf(X1p[0]).x);    // DC
        zb = make_float2(unpackbf(X0p[64]).x, unpackbf(X1p[64]).x);   // Nyquist
      } else {
        float2 x0 = unpackbf(X0p[lane]), x1 = unpackbf(X1p[lane]);
        za = make_float2(x0.x - x1.y, x0.y + x1.x);
        const int mI = 64 - lane;
        float2 y0 = unpackbf(X0p[mI]), y1 = unpackbf(X1p[mI]);
        zb = make_float2(y0.x + y1.y, y1.x - y0.y);
      }
      bufA[grp][f * 128 + lane]      = za;
      bufA[grp][f * 128 + 64 + lane] = zb;
    }
    float2* R = fft128x2(bufA[grp], bufB[grp], tw, lane, 1);
#pragma unroll
    for (int f = 0; f < 2; ++f) {
      const int jp = batch * 8 + grp * 2 + f;
      if (jp < 60) {
        float2 v0 = R[f * 128 + lane];
        dst[(size_t)(2 * jp) * WO + lane]     = v0.x * scale + bo;
        dst[(size_t)(2 * jp + 1) * WO + lane] = v0.y * scale + bo;
        if (lane < WO - 64) {
          float2 v1 = R[f * 128 + 64 + lane];
          dst[(size_t)(2 * jp) * WO + lane + 64]     = v1.x * scale + bo;
          dst[(size_t)(2 * jp + 1) * WO + lane + 64] = v1.y * scale + bo;
        }
      }
    }
  }
}

// ---------------------------------------------------------------------------
extern "C" void kernel_launch(void* const* d_in, const int* in_sizes, int n_in,
                              void* d_out, int out_size, void* d_ws, size_t ws_size,
                              hipStream_t stream) {
  const float* signal = (const float*)d_in[0];
  const float* wr     = (const float*)d_in[1];
  const float* wi     = (const float*)d_in[2];
  const float* bias   = (const float*)d_in[3];
  float* out = (float*)d_out;

  unsigned int* sig_fr = (unsigned int*)d_out;   // 68.2 MB, dead before inv writes
  unsigned int* out_fr = (unsigned int*)d_ws;    // 136.3 MB
  (void)in_sizes; (void)n_in; (void)out_size; (void)ws_size;

  fwd_fft<<<NB * CIN, 256, 0, stream>>>(signal, sig_fr);
  spec_mm<<<2080, 512, 0, stream>>>(sig_fr, wr, wi, out_fr);
  inv_fft<<<NB * COUT, 256, 0, stream>>>(out_fr, bias, out);
}

// Round 7
// 517.011 us; speedup vs baseline: 2.2125x; 1.0574x over previous
//
#include <hip/hip_runtime.h>
#include <math.h>

#define DI __device__ __forceinline__

constexpr int Hh   = 128;
constexpr int Ww   = 128;
constexpr int WF   = 65;            // W/2+1
constexpr int NBIN = Hh * WF;       // 8320
constexpr int NB   = 32;            // batch
constexpr int CIN  = 64;
constexpr int COUT = 128;
constexpr int HO   = 120;
constexpr int WO   = 120;

typedef __bf16 bf16x8 __attribute__((ext_vector_type(8)));
typedef float  f32x16 __attribute__((ext_vector_type(16)));

// ---- bf16 pack/unpack (RNE) ----
DI unsigned int bfbits(float x) {
  unsigned int u = __float_as_uint(x);
  return (u + 0x7FFFu + ((u >> 16) & 1u)) >> 16;
}
DI unsigned int packbf(float re, float im) { return bfbits(re) | (bfbits(im) << 16); }
DI float2 unpackbf(unsigned int v) {
  return make_float2(__uint_as_float(v << 16), __uint_as_float(v & 0xFFFF0000u));
}

DI f32x16 MFMA32(uint4 a, uint4 b, f32x16 c) {
  return __builtin_amdgcn_mfma_f32_32x32x16_bf16(
      __builtin_bit_cast(bf16x8, a), __builtin_bit_cast(bf16x8, b), c, 0, 0, 0);
}
DI unsigned int rotneg(unsigned int x) { return ((x << 16) | (x >> 16)) ^ 0x80000000u; }
DI uint4 derive(uint4 s) {
  uint4 r; r.x = rotneg(s.x); r.y = rotneg(s.y); r.z = rotneg(s.z); r.w = rotneg(s.w);
  return r;
}

DI void wsync() {
  asm volatile("s_waitcnt lgkmcnt(0)" ::: "memory");
  __builtin_amdgcn_sched_barrier(0);
}

// ---------------------------------------------------------------------------
// Register/shuffle 128-pt DIF FFT. Lane l holds a=x[l], b=x[l+64].
// After: a = X[2*bitrev6(l)], b = X[2*bitrev6(l)+1].
// Inverse: conj inputs, run same DIF, conj outputs (scale handled by caller).
// ---------------------------------------------------------------------------
DI int bitrev6(int l) {
  return ((l & 1) << 5) | ((l & 2) << 3) | ((l & 4) << 1) |
         ((l & 8) >> 1) | ((l & 16) >> 3) | ((l & 32) >> 5);
}
DI float2 cmul(float2 a, float2 b) {
  return make_float2(a.x * b.x - a.y * b.y, a.x * b.y + a.y * b.x);
}
DI float2 sxor(float2 v, int m) {
  return make_float2(__shfl_xor(v.x, m), __shfl_xor(v.y, m));
}
DI void stg(float2& v, int h, float2 tw, int l) {
  float2 p = sxor(v, h);
  float2 s = make_float2(v.x + p.x, v.y + p.y);
  float2 d = make_float2(p.x - v.x, p.y - v.y);
  float2 m = cmul(d, tw);
  v = (l & h) ? m : s;
}
DI void stg1(float2& v, int l) {
  float2 p = sxor(v, 1);
  v = (l & 1) ? make_float2(p.x - v.x, p.y - v.y)
              : make_float2(v.x + p.x, v.y + p.y);
}
// tw[0] = W128^l; tw[1+i] = exp(-i*pi*(l&(h-1))/h), h = 32>>i
DI void twinit(float2* tw, int l) {
  float s_, c_;
  sincosf(-(float)M_PI * (float)l / 64.f, &s_, &c_);
  tw[0] = make_float2(c_, s_);
#pragma unroll
  for (int i = 0; i < 5; ++i) {
    const int h = 32 >> i;
    sincosf(-(float)M_PI * (float)(l & (h - 1)) / (float)h, &s_, &c_);
    tw[1 + i] = make_float2(c_, s_);
  }
}
DI void sfft128x2(float2& a0, float2& b0, float2& a1, float2& b1,
                  const float2* tw, int l) {
  {
    float2 s = make_float2(a0.x + b0.x, a0.y + b0.y);
    float2 d = make_float2(a0.x - b0.x, a0.y - b0.y);
    a0 = s; b0 = cmul(d, tw[0]);
  }
  {
    float2 s = make_float2(a1.x + b1.x, a1.y + b1.y);
    float2 d = make_float2(a1.x - b1.x, a1.y - b1.y);
    a1 = s; b1 = cmul(d, tw[0]);
  }
#pragma unroll
  for (int i = 0; i < 5; ++i) {
    const int h = 32 >> i;
    stg(a0, h, tw[1 + i], l); stg(a1, h, tw[1 + i], l);
    stg(b0, h, tw[1 + i], l); stg(b1, h, tw[1 + i], l);
  }
  stg1(a0, l); stg1(a1, l); stg1(b0, l); stg1(b1, l);
}

// ---------------------------------------------------------------------------
// Forward: one block per (b, i). real 128x128 -> packed bf16 complex 128x65.
// ---------------------------------------------------------------------------
__global__ __launch_bounds__(256) void fwd_fft(const float* __restrict__ sig,
                                               unsigned int* __restrict__ sf) {
  __shared__ unsigned int sImg[NBIN];                       // 33280 B
  __shared__ __align__(16) float2 rowbuf[4][2][128];        // 8 KB

  const int t = threadIdx.x, grp = t >> 6, l = t & 63;
  const size_t img = blockIdx.x;
  const float* src = sig + img * (size_t)(Hh * Ww);
  unsigned int* dst = sf + img * (size_t)NBIN;

  float2 tw[6]; twinit(tw, l);
  const int br = bitrev6(l);

  // ---- phase 1: row rfft (two real rows per complex FFT), ILP-2 ----
  for (int batch = 0; batch < 8; ++batch) {
    float2 a[2], b[2];
#pragma unroll
    for (int f = 0; f < 2; ++f) {
      const int jp = batch * 8 + grp * 2 + f;               // row pair 0..63
      const float* r0 = src + (size_t)(2 * jp) * Ww;
      a[f] = make_float2(r0[l],      r0[Ww + l]);
      b[f] = make_float2(r0[64 + l], r0[Ww + 64 + l]);
    }
    sfft128x2(a[0], b[0], a[1], b[1], tw, l);
#pragma unroll
    for (int f = 0; f < 2; ++f) {
      *(float4*)&rowbuf[grp][f][2 * br] =
          make_float4(a[f].x, a[f].y, b[f].x, b[f].y);      // natural-order scatter
    }
    wsync();
#pragma unroll
    for (int f = 0; f < 2; ++f) {
      const int jp = batch * 8 + grp * 2 + f;
      float2 Zk = rowbuf[grp][f][l];
      float2 Zm = rowbuf[grp][f][(128 - l) & 127];
      sImg[(2 * jp) * WF + l]     = packbf(0.5f * (Zk.x + Zm.x), 0.5f * (Zk.y - Zm.y));
      sImg[(2 * jp + 1) * WF + l] = packbf(0.5f * (Zk.y + Zm.y), 0.5f * (Zm.x - Zk.x));
      if (l == 0) {
        float2 Z64 = rowbuf[grp][f][64];
        sImg[(2 * jp) * WF + 64]     = packbf(Z64.x, 0.f);
        sImg[(2 * jp + 1) * WF + 64] = packbf(Z64.y, 0.f);
      }
    }
    wsync();
  }
  __syncthreads();

  // ---- phase 2: complex FFT along H per column, in-register ----
  for (int batch = 0; batch < 9; ++batch) {
    float2 a[2], b[2]; int wcol[2];
#pragma unroll
    for (int f = 0; f < 2; ++f) {
      const int w = batch * 8 + grp * 2 + f; wcol[f] = w;
      const int wc = (w < WF) ? w : (WF - 1);
      a[f] = unpackbf(sImg[l * WF + wc]);
      b[f] = unpackbf(sImg[(l + 64) * WF + wc]);
    }
    sfft128x2(a[0], b[0], a[1], b[1], tw, l);
#pragma unroll
    for (int f = 0; f < 2; ++f) {
      if (wcol[f] < WF) {
        sImg[(2 * br) * WF + wcol[f]]     = packbf(a[f].x, a[f].y);
        sImg[(2 * br + 1) * WF + wcol[f]] = packbf(b[f].x, b[f].y);
      }
    }
  }
  __syncthreads();

  const uint4* s4 = (const uint4*)sImg;
  uint4* d4 = (uint4*)dst;
  for (int idx = t; idx < NBIN / 4; idx += 256) d4[idx] = s4[idx];
}

// ---------------------------------------------------------------------------
// Spectral contraction via 32x32x16 MFMA (unchanged math from r6).
// 2-deep register prefetch: chunk k+2 issued at iter k.
// ---------------------------------------------------------------------------
constexpr int PT    = 16;
constexpr int PLANE = 260;

__global__ __launch_bounds__(512, 3) void spec_mm(const unsigned int* __restrict__ sf,
                                                  const float* __restrict__ wr,
                                                  const float* __restrict__ wi,
                                                  unsigned int* __restrict__ of) {
  __shared__ unsigned int wbuf[PT * PLANE];
  __shared__ unsigned int sbuf[PT * PLANE];

  const int t = threadIdx.x;
  const int bid = blockIdx.x;
  const int swz = (bid & 7) * 260 + (bid >> 3);
  const int o0 = (swz & 3) * 32;
  const int p0 = (swz >> 2) * PT;

  const int po = t & 3;
  const int ii = (t >> 2) & 7;
  const int rl = (t >> 5) & 15;

  const float* wrp0 = wr + ((size_t)(o0 + rl) * CIN + ii) * NBIN + p0 + po * 4;
  const float* wip0 = wi + ((size_t)(o0 + rl) * CIN + ii) * NBIN + p0 + po * 4;
  const unsigned int* sfp0 = sf + ((size_t)rl * CIN + ii) * NBIN + p0 + po * 4;
  const size_t rowAdv = (size_t)16 * CIN * NBIN;

  auto slotOf = [](int row, int i) {
    return ((((row * 2) + (i >> 2)) ^ ((row >> 2) & 7)) << 2) + (i & 3);
  };
  const int slotLo = slotOf(rl, ii);
  const int slotHi = slotOf(rl + 16, ii);

  const int l = t & 63, wv = t >> 6;
  const int lr = l & 31, lq = l >> 5;
  const int moff = ((((lr * 2) + lq) ^ ((lr >> 2) & 7)) << 2);
  const int pA = 2 * wv, pB = 2 * wv + 1;

  f32x16 aR0 = {}, aI0 = {}, aR1 = {}, aI1 = {};

  float4 w0r[2], w1r[2], w0i[2], w1i[2]; uint4 s0v[2], s1v[2];

#pragma unroll
  for (int s = 0; s < 2; ++s) {
    const size_t adv = (size_t)s * 8 * NBIN;
    w0r[s] = *(const float4*)(wrp0 + adv);  w1r[s] = *(const float4*)(wrp0 + adv + rowAdv);
    w0i[s] = *(const float4*)(wip0 + adv);  w1i[s] = *(const float4*)(wip0 + adv + rowAdv);
    s0v[s] = *(const uint4*)(sfp0 + adv);   s1v[s] = *(const uint4*)(sfp0 + adv + rowAdv);
  }

#pragma unroll
  for (int kq = 0; kq < 8; ++kq) {
    const int cs = kq & 1;
    // ---- pack chunk kq -> LDS ----
    {
      const float* a0 = (const float*)&w0r[cs]; const float* a1 = (const float*)&w1r[cs];
      const float* b0 = (const float*)&w0i[cs]; const float* b1 = (const float*)&w1i[cs];
      const unsigned int* u0 = (const unsigned int*)&s0v[cs];
      const unsigned int* u1 = (const unsigned int*)&s1v[cs];
#pragma unroll
      for (int j = 0; j < 4; ++j) {
        const int pp = (po * 4 + j) * PLANE;
        wbuf[pp + slotLo] = packbf(a0[j], -b0[j]);
        wbuf[pp + slotHi] = packbf(a1[j], -b1[j]);
        sbuf[pp + slotLo] = u0[j];
        sbuf[pp + slotHi] = u1[j];
      }
    }
    // ---- issue chunk kq+2 into the just-freed register set ----
    if (kq < 6) {
      const size_t adv = (size_t)(kq + 2) * 8 * NBIN;
      w0r[cs] = *(const float4*)(wrp0 + adv);  w1r[cs] = *(const float4*)(wrp0 + adv + rowAdv);
      w0i[cs] = *(const float4*)(wip0 + adv);  w1i[cs] = *(const float4*)(wip0 + adv + rowAdv);
      s0v[cs] = *(const uint4*)(sfp0 + adv);   s1v[cs] = *(const uint4*)(sfp0 + adv + rowAdv);
    }
    __syncthreads();

    {
      const uint4 a = *(const uint4*)&wbuf[pA * PLANE + moff];
      const uint4 s = *(const uint4*)&sbuf[pA * PLANE + moff];
      aR0 = MFMA32(a, s, aR0);
      aI0 = MFMA32(a, derive(s), aI0);
    }
    {
      const uint4 a = *(const uint4*)&wbuf[pB * PLANE + moff];
      const uint4 s = *(const uint4*)&sbuf[pB * PLANE + moff];
      aR1 = MFMA32(a, s, aR1);
      aI1 = MFMA32(a, derive(s), aI1);
    }
    __syncthreads();
  }

  const int b = lr;
#pragma unroll
  for (int r = 0; r < 16; ++r) {
    const int o = o0 + (r & 3) + 8 * (r >> 2) + 4 * lq;
    uint2 v;
    v.x = packbf(aR0[r], aI0[r]);
    v.y = packbf(aR1[r], aI1[r]);
    *(uint2*)(of + ((size_t)b * COUT + o) * NBIN + p0 + 2 * wv) = v;
  }
}

// ---------------------------------------------------------------------------
// Inverse: one block per (b, o). packed bf16 128x65 -> real 120x120 (+bias).
// y = conj(DIF(conj z)) / 16384 both directions; rows write straight to global.
// ---------------------------------------------------------------------------
__global__ __launch_bounds__(256) void inv_fft(const unsigned int* __restrict__ of,
                                               const float* __restrict__ bias,
                                               float* __restrict__ out) {
  __shared__ unsigned int sImg[NBIN];

  const int t = threadIdx.x, grp = t >> 6, l = t & 63;
  const size_t img = blockIdx.x;                 // b*COUT + o
  const unsigned int* src = of + img * (size_t)NBIN;
  float* dst = out + img * (size_t)(HO * WO);
  const float bo = bias[img & (COUT - 1)];

  float2 tw[6]; twinit(tw, l);
  const int br = bitrev6(l);

  const uint4* s4 = (const uint4*)src;
  uint4* d4 = (uint4*)sImg;
  for (int idx = t; idx < NBIN / 4; idx += 256) d4[idx] = s4[idx];
  __syncthreads();

  // ---- phase 1: inverse FFT along H per column (unscaled) ----
  for (int batch = 0; batch < 9; ++batch) {
    float2 a[2], b[2]; int wcol[2];
#pragma unroll
    for (int f = 0; f < 2; ++f) {
      const int w = batch * 8 + grp * 2 + f; wcol[f] = w;
      const int wc = (w < WF) ? w : (WF - 1);
      float2 za = unpackbf(sImg[l * WF + wc]);
      float2 zb = unpackbf(sImg[(l + 64) * WF + wc]);
      a[f] = make_float2(za.x, -za.y);           // conj in
      b[f] = make_float2(zb.x, -zb.y);
    }
    sfft128x2(a[0], b[0], a[1], b[1], tw, l);
#pragma unroll
    for (int f = 0; f < 2; ++f) {
      if (wcol[f] < WF) {
        sImg[(2 * br) * WF + wcol[f]]     = packbf(a[f].x, -a[f].y);   // conj out
        sImg[(2 * br + 1) * WF + wcol[f]] = packbf(b[f].x, -b[f].y);
      }
    }
  }
  __syncthreads();

  // ---- phase 2: irfft rows (pair trick) -> crop -> scale -> +bias ----
  const float sc = 1.f / 16384.f;
  for (int batch = 0; batch < 8; ++batch) {      // row pairs 0..59 (+4 pad)
    float2 a[2], b[2]; int jpv[2];
#pragma unroll
    for (int f = 0; f < 2; ++f) {
      const int jp = batch * 8 + grp * 2 + f; jpv[f] = jp;
      const int jc = (jp < 60) ? jp : 59;
      const unsigned int* X0p = &sImg[(size_t)(2 * jc) * WF];
      const unsigned int* X1p = X0p + WF;
      float2 za, zb;
      if (l == 0) {
        za = make_float2(unpackbf(X0p[0]).x,  unpackbf(X1p[0]).x);    // DC
        zb = make_float2(unpackbf(X0p[64]).x, unpackbf(X1p[64]).x);   // Nyquist
      } else {
        float2 x0 = unpackbf(X0p[l]), x1 = unpackbf(X1p[l]);
        za = make_float2(x0.x - x1.y, x0.y + x1.x);                   // Z[l]
        const int mI = 64 - l;
        float2 y0 = unpackbf(X0p[mI]), y1 = unpackbf(X1p[mI]);
        zb = make_float2(y0.x + y1.y, y1.x - y0.y);                   // Z[64+l]
      }
      a[f] = make_float2(za.x, -za.y);           // conj in
      b[f] = make_float2(zb.x, -zb.y);
    }
    sfft128x2(a[0], b[0], a[1], b[1], tw, l);
    const int n0 = 2 * br;
#pragma unroll
    for (int f = 0; f < 2; ++f) {
      const int jp = jpv[f];
      if (jp < 60 && n0 < WO) {
        // y[n] = conj(out): row0 = Re, row1 = -Im
        float2 r0 = make_float2(a[f].x * sc + bo,  b[f].x * sc + bo);
        float2 r1 = make_float2(-a[f].y * sc + bo, -b[f].y * sc + bo);
        *(float2*)(dst + (size_t)(2 * jp) * WO + n0)     = r0;
        *(float2*)(dst + (size_t)(2 * jp + 1) * WO + n0) = r1;
      }
    }
  }
}

// ---------------------------------------------------------------------------
extern "C" void kernel_launch(void* const* d_in, const int* in_sizes, int n_in,
                              void* d_out, int out_size, void* d_ws, size_t ws_size,
                              hipStream_t stream) {
  const float* signal = (const float*)d_in[0];
  const float* wr     = (const float*)d_in[1];
  const float* wi     = (const float*)d_in[2];
  const float* bias   = (const float*)d_in[3];
  float* out = (float*)d_out;

  unsigned int* sig_fr = (unsigned int*)d_out;   // 68.2 MB, dead before inv writes
  unsigned int* out_fr = (unsigned int*)d_ws;    // 136.3 MB
  (void)in_sizes; (void)n_in; (void)out_size; (void)ws_size;

  fwd_fft<<<NB * CIN, 256, 0, stream>>>(signal, sig_fr);
  spec_mm<<<2080, 512, 0, stream>>>(sig_fr, wr, wi, out_fr);
  inv_fft<<<NB * COUT, 256, 0, stream>>>(out_fr, bias, out);
}

// Round 8
// 489.790 us; speedup vs baseline: 2.3354x; 1.0556x over previous
//
#include <hip/hip_runtime.h>
#include <math.h>

#define DI __device__ __forceinline__

constexpr int Hh   = 128;
constexpr int Ww   = 128;
constexpr int WF   = 65;            // W/2+1
constexpr int NBIN = Hh * WF;       // 8320
constexpr int NB   = 32;            // batch
constexpr int CIN  = 64;
constexpr int COUT = 128;
constexpr int HO   = 120;
constexpr int WO   = 120;

typedef __bf16 bf16x8 __attribute__((ext_vector_type(8)));
typedef float  f32x16 __attribute__((ext_vector_type(16)));

// ---- bf16 pack/unpack (RNE) ----
DI unsigned int bfbits(float x) {
  unsigned int u = __float_as_uint(x);
  return (u + 0x7FFFu + ((u >> 16) & 1u)) >> 16;
}
DI unsigned int packbf(float re, float im) { return bfbits(re) | (bfbits(im) << 16); }
DI float2 unpackbf(unsigned int v) {
  return make_float2(__uint_as_float(v << 16), __uint_as_float(v & 0xFFFF0000u));
}

DI f32x16 MFMA32(uint4 a, uint4 b, f32x16 c) {
  return __builtin_amdgcn_mfma_f32_32x32x16_bf16(
      __builtin_bit_cast(bf16x8, a), __builtin_bit_cast(bf16x8, b), c, 0, 0, 0);
}
DI unsigned int rotneg(unsigned int x) { return ((x << 16) | (x >> 16)) ^ 0x80000000u; }
DI uint4 derive(uint4 s) {
  uint4 r; r.x = rotneg(s.x); r.y = rotneg(s.y); r.z = rotneg(s.z); r.w = rotneg(s.w);
  return r;
}

// ---------------------------------------------------------------------------
// Register/shuffle 128-pt DIF FFT. Lane l holds a=x[l], b=x[l+64].
// After: a = X[2*bitrev6(l)], b = X[2*bitrev6(l)+1].
// Inverse: conj inputs, run same DIF, conj outputs.
// ---------------------------------------------------------------------------
DI int bitrev6(int l) {
  return ((l & 1) << 5) | ((l & 2) << 3) | ((l & 4) << 1) |
         ((l & 8) >> 1) | ((l & 16) >> 3) | ((l & 32) >> 5);
}
DI float2 cmul(float2 a, float2 b) {
  return make_float2(a.x * b.x - a.y * b.y, a.x * b.y + a.y * b.x);
}
DI float2 sxor(float2 v, int m) {
  return make_float2(__shfl_xor(v.x, m), __shfl_xor(v.y, m));
}
DI float bpermf(int addr, float v) {
  return __int_as_float(__builtin_amdgcn_ds_bpermute(addr, __float_as_int(v)));
}
DI void stg(float2& v, int h, float2 tw, int l) {
  float2 p = sxor(v, h);
  float2 s = make_float2(v.x + p.x, v.y + p.y);
  float2 d = make_float2(p.x - v.x, p.y - v.y);
  float2 m = cmul(d, tw);
  v = (l & h) ? m : s;
}
DI void stg1(float2& v, int l) {
  float2 p = sxor(v, 1);
  v = (l & 1) ? make_float2(p.x - v.x, p.y - v.y)
              : make_float2(v.x + p.x, v.y + p.y);
}
// tw[0] = W128^l; tw[1+i] = exp(-i*pi*(l&(h-1))/h), h = 32>>i   (fast sincos)
DI void twinit(float2* tw, int l) {
  float s_, c_;
  __sincosf(-(float)M_PI * (float)l / 64.f, &s_, &c_);
  tw[0] = make_float2(c_, s_);
#pragma unroll
  for (int i = 0; i < 5; ++i) {
    const int h = 32 >> i;
    __sincosf(-(float)M_PI * (float)(l & (h - 1)) / (float)h, &s_, &c_);
    tw[1 + i] = make_float2(c_, s_);
  }
}
DI void sfft128x2(float2& a0, float2& b0, float2& a1, float2& b1,
                  const float2* tw, int l) {
  {
    float2 s = make_float2(a0.x + b0.x, a0.y + b0.y);
    float2 d = make_float2(a0.x - b0.x, a0.y - b0.y);
    a0 = s; b0 = cmul(d, tw[0]);
  }
  {
    float2 s = make_float2(a1.x + b1.x, a1.y + b1.y);
    float2 d = make_float2(a1.x - b1.x, a1.y - b1.y);
    a1 = s; b1 = cmul(d, tw[0]);
  }
#pragma unroll
  for (int i = 0; i < 5; ++i) {
    const int h = 32 >> i;
    stg(a0, h, tw[1 + i], l); stg(a1, h, tw[1 + i], l);
    stg(b0, h, tw[1 + i], l); stg(b1, h, tw[1 + i], l);
  }
  stg1(a0, l); stg1(a1, l); stg1(b0, l); stg1(b1, l);
}

// ---------------------------------------------------------------------------
// Forward: one block per (b, i). real 128x128 -> packed bf16 complex 128x65.
// rfft unpack done fully in-register via ds_bpermute (no LDS round-trip).
// ---------------------------------------------------------------------------
__global__ __launch_bounds__(256) void fwd_fft(const float* __restrict__ sig,
                                               unsigned int* __restrict__ sf) {
  __shared__ unsigned int sImg[NBIN];                       // 33280 B

  const int t = threadIdx.x, grp = t >> 6, l = t & 63;
  const size_t img = blockIdx.x;
  const float* src = sig + img * (size_t)(Hh * Ww);
  unsigned int* dst = sf + img * (size_t)NBIN;

  float2 tw[6]; twinit(tw, l);
  const int br = bitrev6(l);
  // bpermute source lanes for the conjugate-symmetric unpack:
  const int sk4 = bitrev6(l >> 1) * 4;                 // holder of Z[l]
  const int im  = (128 - l) & 127;
  const int sm4 = bitrev6(im >> 1) * 4;                // holder of Z[128-l]
  const bool podd = (l & 1) != 0;                      // parity of l == parity of 128-l

  // ---- phase 1: row rfft (two real rows per complex FFT), ILP-2 ----
  for (int batch = 0; batch < 8; ++batch) {
    float2 a[2], b[2];
#pragma unroll
    for (int f = 0; f < 2; ++f) {
      const int jp = batch * 8 + grp * 2 + f;               // row pair 0..63
      const float* r0 = src + (size_t)(2 * jp) * Ww;
      a[f] = make_float2(r0[l],      r0[Ww + l]);
      b[f] = make_float2(r0[64 + l], r0[Ww + 64 + l]);
    }
    sfft128x2(a[0], b[0], a[1], b[1], tw, l);
#pragma unroll
    for (int f = 0; f < 2; ++f) {
      const int jp = batch * 8 + grp * 2 + f;
      // gather Z[l], Z[128-l], Z[64] from the bitrev-distributed registers
      float axk = bpermf(sk4, a[f].x), ayk = bpermf(sk4, a[f].y);
      float bxk = bpermf(sk4, b[f].x), byk = bpermf(sk4, b[f].y);
      float axm = bpermf(sm4, a[f].x), aym = bpermf(sm4, a[f].y);
      float bxm = bpermf(sm4, b[f].x), bym = bpermf(sm4, b[f].y);
      float z64x = bpermf(4, a[f].x),  z64y = bpermf(4, a[f].y);   // Z[64] in lane 1.a
      float2 Zk = podd ? make_float2(bxk, byk) : make_float2(axk, ayk);
      float2 Zm = podd ? make_float2(bxm, bym) : make_float2(axm, aym);
      sImg[(2 * jp) * WF + l]     = packbf(0.5f * (Zk.x + Zm.x), 0.5f * (Zk.y - Zm.y));
      sImg[(2 * jp + 1) * WF + l] = packbf(0.5f * (Zk.y + Zm.y), 0.5f * (Zm.x - Zk.x));
      if (l == 0) {
        sImg[(2 * jp) * WF + 64]     = packbf(z64x, 0.f);
        sImg[(2 * jp + 1) * WF + 64] = packbf(z64y, 0.f);
      }
    }
  }
  __syncthreads();

  // ---- phase 2: complex FFT along H per column, in-register ----
  for (int batch = 0; batch < 9; ++batch) {
    float2 a[2], b[2]; int wcol[2];
#pragma unroll
    for (int f = 0; f < 2; ++f) {
      const int w = batch * 8 + grp * 2 + f; wcol[f] = w;
      const int wc = (w < WF) ? w : (WF - 1);
      a[f] = unpackbf(sImg[l * WF + wc]);
      b[f] = unpackbf(sImg[(l + 64) * WF + wc]);
    }
    sfft128x2(a[0], b[0], a[1], b[1], tw, l);
#pragma unroll
    for (int f = 0; f < 2; ++f) {
      if (wcol[f] < WF) {
        sImg[(2 * br) * WF + wcol[f]]     = packbf(a[f].x, a[f].y);
        sImg[(2 * br + 1) * WF + wcol[f]] = packbf(b[f].x, b[f].y);
      }
    }
  }
  __syncthreads();

  const uint4* s4 = (const uint4*)sImg;
  uint4* d4 = (uint4*)dst;
  for (int idx = t; idx < NBIN / 4; idx += 256) d4[idx] = s4[idx];
}

// ---------------------------------------------------------------------------
// Spectral contraction via 32x32x16 MFMA (r6-proven config).
// Tile: 16 bins x 32 o x 32 b; 512 thr; 8 chunks of 8 i; 1-deep prefetch.
// ---------------------------------------------------------------------------
constexpr int PT    = 16;
constexpr int PLANE = 260;

__global__ __launch_bounds__(512, 4) void spec_mm(const unsigned int* __restrict__ sf,
                                                  const float* __restrict__ wr,
                                                  const float* __restrict__ wi,
                                                  unsigned int* __restrict__ of) {
  __shared__ unsigned int wbuf[PT * PLANE];
  __shared__ unsigned int sbuf[PT * PLANE];

  const int t = threadIdx.x;
  const int bid = blockIdx.x;
  const int swz = (bid & 7) * 260 + (bid >> 3);
  const int o0 = (swz & 3) * 32;
  const int p0 = (swz >> 2) * PT;

  const int po = t & 3;
  const int ii = (t >> 2) & 7;
  const int rl = (t >> 5) & 15;

  const float* wrp0 = wr + ((size_t)(o0 + rl) * CIN + ii) * NBIN + p0 + po * 4;
  const float* wip0 = wi + ((size_t)(o0 + rl) * CIN + ii) * NBIN + p0 + po * 4;
  const unsigned int* sfp0 = sf + ((size_t)rl * CIN + ii) * NBIN + p0 + po * 4;
  const size_t rowAdv = (size_t)16 * CIN * NBIN;

  auto slotOf = [](int row, int i) {
    return ((((row * 2) + (i >> 2)) ^ ((row >> 2) & 7)) << 2) + (i & 3);
  };
  const int slotLo = slotOf(rl, ii);
  const int slotHi = slotOf(rl + 16, ii);

  const int l = t & 63, wv = t >> 6;
  const int lr = l & 31, lq = l >> 5;
  const int moff = ((((lr * 2) + lq) ^ ((lr >> 2) & 7)) << 2);
  const int pA = 2 * wv, pB = 2 * wv + 1;

  f32x16 aR0 = {}, aI0 = {}, aR1 = {}, aI1 = {};

  float4 w0r, w1r, w0i, w1i; uint4 s0v, s1v;
  {
    w0r = *(const float4*)(wrp0);          w1r = *(const float4*)(wrp0 + rowAdv);
    w0i = *(const float4*)(wip0);          w1i = *(const float4*)(wip0 + rowAdv);
    s0v = *(const uint4*)(sfp0);           s1v = *(const uint4*)(sfp0 + rowAdv);
  }

  for (int kq = 0; kq < 8; ++kq) {
    // ---- pack current chunk regs -> LDS ----
    const float* a0 = (const float*)&w0r;  const float* a1 = (const float*)&w1r;
    const float* b0 = (const float*)&w0i;  const float* b1 = (const float*)&w1i;
    const unsigned int* u0 = (const unsigned int*)&s0v;
    const unsigned int* u1 = (const unsigned int*)&s1v;
#pragma unroll
    for (int j = 0; j < 4; ++j) {
      const int pp = (po * 4 + j) * PLANE;
      wbuf[pp + slotLo] = packbf(a0[j], -b0[j]);
      wbuf[pp + slotHi] = packbf(a1[j], -b1[j]);
      sbuf[pp + slotLo] = u0[j];
      sbuf[pp + slotHi] = u1[j];
    }
    // ---- issue next chunk's loads before the barrier (latency hiding) ----
    if (kq < 7) {
      const size_t adv = (size_t)(kq + 1) * 8 * NBIN;
      w0r = *(const float4*)(wrp0 + adv);  w1r = *(const float4*)(wrp0 + adv + rowAdv);
      w0i = *(const float4*)(wip0 + adv);  w1i = *(const float4*)(wip0 + adv + rowAdv);
      s0v = *(const uint4*)(sfp0 + adv);   s1v = *(const uint4*)(sfp0 + adv + rowAdv);
    }
    __syncthreads();

    {
      const uint4 a = *(const uint4*)&wbuf[pA * PLANE + moff];
      const uint4 s = *(const uint4*)&sbuf[pA * PLANE + moff];
      aR0 = MFMA32(a, s, aR0);
      aI0 = MFMA32(a, derive(s), aI0);
    }
    {
      const uint4 a = *(const uint4*)&wbuf[pB * PLANE + moff];
      const uint4 s = *(const uint4*)&sbuf[pB * PLANE + moff];
      aR1 = MFMA32(a, s, aR1);
      aI1 = MFMA32(a, derive(s), aI1);
    }
    __syncthreads();
  }

  const int b = lr;
#pragma unroll
  for (int r = 0; r < 16; ++r) {
    const int o = o0 + (r & 3) + 8 * (r >> 2) + 4 * lq;
    uint2 v;
    v.x = packbf(aR0[r], aI0[r]);
    v.y = packbf(aR1[r], aI1[r]);
    *(uint2*)(of + ((size_t)b * COUT + o) * NBIN + p0 + 2 * wv) = v;
  }
}

// ---------------------------------------------------------------------------
// Inverse: one block per (b, o). packed bf16 128x65 -> real 120x120 (+bias).
// y = conj(DIF(conj z)) / 16384; rows write straight to global.
// ---------------------------------------------------------------------------
__global__ __launch_bounds__(256) void inv_fft(const unsigned int* __restrict__ of,
                                               const float* __restrict__ bias,
                                               float* __restrict__ out) {
  __shared__ unsigned int sImg[NBIN];

  const int t = threadIdx.x, grp = t >> 6, l = t & 63;
  const size_t img = blockIdx.x;                 // b*COUT + o
  const unsigned int* src = of + img * (size_t)NBIN;
  float* dst = out + img * (size_t)(HO * WO);
  const float bo = bias[img & (COUT - 1)];

  float2 tw[6]; twinit(tw, l);
  const int br = bitrev6(l);

  const uint4* s4 = (const uint4*)src;
  uint4* d4 = (uint4*)sImg;
  for (int idx = t; idx < NBIN / 4; idx += 256) d4[idx] = s4[idx];
  __syncthreads();

  // ---- phase 1: inverse FFT along H per column (unscaled) ----
  for (int batch = 0; batch < 9; ++batch) {
    float2 a[2], b[2]; int wcol[2];
#pragma unroll
    for (int f = 0; f < 2; ++f) {
      const int w = batch * 8 + grp * 2 + f; wcol[f] = w;
      const int wc = (w < WF) ? w : (WF - 1);
      float2 za = unpackbf(sImg[l * WF + wc]);
      float2 zb = unpackbf(sImg[(l + 64) * WF + wc]);
      a[f] = make_float2(za.x, -za.y);           // conj in
      b[f] = make_float2(zb.x, -zb.y);
    }
    sfft128x2(a[0], b[0], a[1], b[1], tw, l);
#pragma unroll
    for (int f = 0; f < 2; ++f) {
      if (wcol[f] < WF) {
        sImg[(2 * br) * WF + wcol[f]]     = packbf(a[f].x, -a[f].y);   // conj out
        sImg[(2 * br + 1) * WF + wcol[f]] = packbf(b[f].x, -b[f].y);
      }
    }
  }
  __syncthreads();

  // ---- phase 2: irfft rows (pair trick) -> crop -> scale -> +bias ----
  const float sc = 1.f / 16384.f;
  for (int batch = 0; batch < 8; ++batch) {      // row pairs 0..59 (+4 pad)
    float2 a[2], b[2]; int jpv[2];
#pragma unroll
    for (int f = 0; f < 2; ++f) {
      const int jp = batch * 8 + grp * 2 + f; jpv[f] = jp;
      const int jc = (jp < 60) ? jp : 59;
      const unsigned int* X0p = &sImg[(size_t)(2 * jc) * WF];
      const unsigned int* X1p = X0p + WF;
      float2 za, zb;
      if (l == 0) {
        za = make_float2(unpackbf(X0p[0]).x,  unpackbf(X1p[0]).x);    // DC
        zb = make_float2(unpackbf(X0p[64]).x, unpackbf(X1p[64]).x);   // Nyquist
      } else {
        float2 x0 = unpackbf(X0p[l]), x1 = unpackbf(X1p[l]);
        za = make_float2(x0.x - x1.y, x0.y + x1.x);                   // Z[l]
        const int mI = 64 - l;
        float2 y0 = unpackbf(X0p[mI]), y1 = unpackbf(X1p[mI]);
        zb = make_float2(y0.x + y1.y, y1.x - y0.y);                   // Z[64+l]
      }
      a[f] = make_float2(za.x, -za.y);           // conj in
      b[f] = make_float2(zb.x, -zb.y);
    }
    sfft128x2(a[0], b[0], a[1], b[1], tw, l);
    const int n0 = 2 * br;
#pragma unroll
    for (int f = 0; f < 2; ++f) {
      const int jp = jpv[f];
      if (jp < 60 && n0 < WO) {
        // y[n] = conj(out): row0 = Re, row1 = -Im
        float2 r0 = make_float2(a[f].x * sc + bo,  b[f].x * sc + bo);
        float2 r1 = make_float2(-a[f].y * sc + bo, -b[f].y * sc + bo);
        *(float2*)(dst + (size_t)(2 * jp) * WO + n0)     = r0;
        *(float2*)(dst + (size_t)(2 * jp + 1) * WO + n0) = r1;
      }
    }
  }
}

// ---------------------------------------------------------------------------
extern "C" void kernel_launch(void* const* d_in, const int* in_sizes, int n_in,
                              void* d_out, int out_size, void* d_ws, size_t ws_size,
                              hipStream_t stream) {
  const float* signal = (const float*)d_in[0];
  const float* wr     = (const float*)d_in[1];
  const float* wi     = (const float*)d_in[2];
  const float* bias   = (const float*)d_in[3];
  float* out = (float*)d_out;

  unsigned int* sig_fr = (unsigned int*)d_out;   // 68.2 MB, dead before inv writes
  unsigned int* out_fr = (unsigned int*)d_ws;    // 136.3 MB
  (void)in_sizes; (void)n_in; (void)out_size; (void)ws_size;

  fwd_fft<<<NB * CIN, 256, 0, stream>>>(signal, sig_fr);
  spec_mm<<<2080, 512, 0, stream>>>(sig_fr, wr, wi, out_fr);
  inv_fft<<<NB * COUT, 256, 0, stream>>>(out_fr, bias, out);
}